// Round 1
// baseline (45415.237 us; speedup 1.0000x reference)
//
#include <hip/hip_runtime.h>
#include <math.h>

#define HID 512
#define B 64
#define SEQT 1024
#define FUT 16
#define TT (SEQT + FUT)
#define NWG 256
#define TPB 512
#define NWAVE 8          // TPB/64
#define JPW 2            // hidden units owned per WG = HID/NWG
#define HB (HID * B)     // one h buffer, floats

// ---------------- grid barrier (device-scope, monotonic counter) -------------
__device__ inline void gbar(int* cnt, int target) {
  __syncthreads();
  if (threadIdx.x == 0) {
    __threadfence();  // make h writes visible device-wide before arrival
    __hip_atomic_fetch_add(cnt, 1, __ATOMIC_RELEASE, __HIP_MEMORY_SCOPE_AGENT);
    while (__hip_atomic_load(cnt, __ATOMIC_ACQUIRE, __HIP_MEMORY_SCOPE_AGENT) < target) {
      __builtin_amdgcn_s_sleep(2);
    }
  }
  __syncthreads();
}

__global__ void __launch_bounds__(TPB) zero_ws(float* ws, int n) {
  int i = blockIdx.x * blockDim.x + threadIdx.x;
  if (i < n) ws[i] = 0.0f;
}

// ---------------- persistent 2-layer LSTM kernel -----------------------------
// ws layout (floats): [0..15] barrier counter (int at 0) ; h1 double buffer
// 2*HB ; h2 double buffer 2*HB.
__global__ void __launch_bounds__(TPB) rnn_persist(
    const float* __restrict__ x,
    const float* __restrict__ W1, const float* __restrict__ bW1,
    const float* __restrict__ U1, const float* __restrict__ bU1,
    const float* __restrict__ W2, const float* __restrict__ bW2,
    const float* __restrict__ U2, const float* __restrict__ bU2,
    const float* __restrict__ lw, const float* __restrict__ lb,
    float* out, float* ws)
{
  __shared__ float red[NWAVE][8][B];   // per-wave partial dots, 16 KB
  __shared__ float outred[NWAVE][B];   // WG0 output-head reduction, 2 KB
  __shared__ float c1s[JPW][B], c2s[JPW][B];
  __shared__ float w1c[8], bs1[8], bs2[8];

  int* cnt   = (int*)ws;
  float* h1b = ws + 16;
  float* h2b = h1b + 2 * HB;

  const int wg   = blockIdx.x;
  const int j0   = wg * JPW;
  const int tid  = threadIdx.x;
  const int lane = tid & 63;
  // wave id, made explicitly wave-uniform so weight addresses scalarize
  const int wvu  = __builtin_amdgcn_readfirstlane(tid >> 6);
  const int kb   = wvu << 6;  // this wave's 64-wide k-chunk

  if (tid < JPW * B) { c1s[tid >> 6][lane] = 0.f; c2s[tid >> 6][lane] = 0.f; }
  if (tid < 8) {
    const int g = tid >> 1, jl = tid & 1;
    const int row = g * HID + j0 + jl;
    w1c[tid] = W1[row];
    bs1[tid] = bW1[row] + bU1[row];
    bs2[tid] = bW2[row] + bU2[row];
  }
  __syncthreads();

  // uniform weight row base pointers (rows {g*512 + j0 + jl}, g=0..3, jl=0..1)
  const float* u1p[8]; const float* w2p[8]; const float* u2p[8];
  #pragma unroll
  for (int r = 0; r < 8; ++r) {
    const int row = (r >> 1) * HID + j0 + (r & 1);
    u1p[r] = U1 + (size_t)row * HID + kb;
    w2p[r] = W2 + (size_t)row * HID + kb;
    u2p[r] = U2 + (size_t)row * HID + kb;
  }
  const float lbv = lb[0];

  int bar = 0;
  for (int t = 0; t < TT; ++t) {
    const float* h1old = h1b + ((t + 1) & 1) * HB;  // h1(t-1)
    float*       h1new = h1b + (t & 1) * HB;        // h1(t)
    const float* h2old = h2b + ((t + 1) & 1) * HB;  // h2(t-1)
    float*       h2new = h2b + (t & 1) * HB;        // h2(t)

    // ---------------- phase 1: gates1 = x*W1 + U1 h1(t-1) + b ----------------
    {
      const float* hp = h1old + (size_t)kb * B;
      float a0=0.f,a1=0.f,a2=0.f,a3=0.f,a4=0.f,a5=0.f,a6=0.f,a7=0.f;
      #pragma unroll 8
      for (int k = 0; k < 64; ++k) {
        const float hv = hp[k * B + lane];
        a0 = fmaf(u1p[0][k], hv, a0);
        a1 = fmaf(u1p[1][k], hv, a1);
        a2 = fmaf(u1p[2][k], hv, a2);
        a3 = fmaf(u1p[3][k], hv, a3);
        a4 = fmaf(u1p[4][k], hv, a4);
        a5 = fmaf(u1p[5][k], hv, a5);
        a6 = fmaf(u1p[6][k], hv, a6);
        a7 = fmaf(u1p[7][k], hv, a7);
      }
      red[wvu][0][lane]=a0; red[wvu][1][lane]=a1; red[wvu][2][lane]=a2; red[wvu][3][lane]=a3;
      red[wvu][4][lane]=a4; red[wvu][5][lane]=a5; red[wvu][6][lane]=a6; red[wvu][7][lane]=a7;
    }
    __syncthreads();

    // cell-1 elementwise (2 j's x 64 b = 128 threads)
    if (tid < JPW * B) {
      const int jl = tid >> 6, b = tid & 63;
      const float xv = (t < SEQT) ? x[(size_t)b * SEQT + t]
                                  : out[(size_t)b * TT + (t - 1)];
      float gate[4];
      #pragma unroll
      for (int g = 0; g < 4; ++g) {
        const int r = g * 2 + jl;
        float s = bs1[r] + xv * w1c[r];
        #pragma unroll
        for (int w = 0; w < NWAVE; ++w) s += red[w][r][b];
        gate[g] = s;
      }
      const float c = gate[1] * c1s[jl][b] + gate[0] * gate[2];
      c1s[jl][b] = c;
      h1new[(size_t)(j0 + jl) * B + b] = gate[3] * tanhf(c);
    }

    ++bar;
    gbar(cnt, NWG * bar);

    // WG0: output head for step t-1 (teacher-forced region), overlapped with
    // other WGs' phase 2. h2(t-1) is complete (barrier above covers phase2(t-1)).
    if (wg == 0 && t >= 1 && t <= SEQT - 1) {
      const float* hb2 = h2old + (size_t)(wvu * 64) * B;
      const float* lwp = lw + wvu * 64;
      float p = 0.f;
      #pragma unroll 8
      for (int j = 0; j < 64; ++j) p = fmaf(lwp[j], hb2[j * B + lane], p);
      outred[wvu][lane] = p;
      __syncthreads();
      if (tid < B) {
        float o = lbv;
        #pragma unroll
        for (int s = 0; s < NWAVE; ++s) o += outred[s][tid];
        out[(size_t)tid * TT + (t - 1)] = o;
      }
      __syncthreads();
    }

    // ---------------- phase 2: gates2 = W2 h1(t) + U2 h2(t-1) + b ------------
    {
      const float* h1p = h1new + (size_t)kb * B;
      const float* h2p = h2old + (size_t)kb * B;
      float s0=0.f,s1=0.f,s2=0.f,s3=0.f,s4=0.f,s5=0.f,s6=0.f,s7=0.f;
      float q0=0.f,q1=0.f,q2=0.f,q3=0.f,q4=0.f,q5=0.f,q6=0.f,q7=0.f;
      #pragma unroll 4
      for (int k = 0; k < 64; ++k) {
        const float h1v = h1p[k * B + lane];
        const float h2v = h2p[k * B + lane];
        s0 = fmaf(w2p[0][k], h1v, s0); q0 = fmaf(u2p[0][k], h2v, q0);
        s1 = fmaf(w2p[1][k], h1v, s1); q1 = fmaf(u2p[1][k], h2v, q1);
        s2 = fmaf(w2p[2][k], h1v, s2); q2 = fmaf(u2p[2][k], h2v, q2);
        s3 = fmaf(w2p[3][k], h1v, s3); q3 = fmaf(u2p[3][k], h2v, q3);
        s4 = fmaf(w2p[4][k], h1v, s4); q4 = fmaf(u2p[4][k], h2v, q4);
        s5 = fmaf(w2p[5][k], h1v, s5); q5 = fmaf(u2p[5][k], h2v, q5);
        s6 = fmaf(w2p[6][k], h1v, s6); q6 = fmaf(u2p[6][k], h2v, q6);
        s7 = fmaf(w2p[7][k], h1v, s7); q7 = fmaf(u2p[7][k], h2v, q7);
      }
      red[wvu][0][lane]=s0+q0; red[wvu][1][lane]=s1+q1;
      red[wvu][2][lane]=s2+q2; red[wvu][3][lane]=s3+q3;
      red[wvu][4][lane]=s4+q4; red[wvu][5][lane]=s5+q5;
      red[wvu][6][lane]=s6+q6; red[wvu][7][lane]=s7+q7;
    }
    __syncthreads();

    // cell-2 elementwise
    if (tid < JPW * B) {
      const int jl = tid >> 6, b = tid & 63;
      float gate[4];
      #pragma unroll
      for (int g = 0; g < 4; ++g) {
        const int r = g * 2 + jl;
        float s = bs2[r];
        #pragma unroll
        for (int w = 0; w < NWAVE; ++w) s += red[w][r][b];
        gate[g] = s;
      }
      const float c = gate[1] * c2s[jl][b] + gate[0] * gate[2];
      c2s[jl][b] = c;
      h2new[(size_t)(j0 + jl) * B + b] = gate[3] * tanhf(c);
    }
    __syncthreads();  // protect red[] before next step's phase-1 writes

    // Autoregressive region: out(t) must be globally visible before phase1(t+1)
    if (t >= SEQT - 1) {
      ++bar;
      gbar(cnt, NWG * bar);
      if (wg == 0) {
        const float* hb2 = h2new + (size_t)(wvu * 64) * B;
        const float* lwp = lw + wvu * 64;
        float p = 0.f;
        #pragma unroll 8
        for (int j = 0; j < 64; ++j) p = fmaf(lwp[j], hb2[j * B + lane], p);
        outred[wvu][lane] = p;
        __syncthreads();
        if (tid < B) {
          float o = lbv;
          #pragma unroll
          for (int s = 0; s < NWAVE; ++s) o += outred[s][tid];
          out[(size_t)tid * TT + t] = o;
        }
        __syncthreads();
      }
      ++bar;
      gbar(cnt, NWG * bar);
    }
  }
}

extern "C" void kernel_launch(void* const* d_in, const int* in_sizes, int n_in,
                              void* d_out, int out_size, void* d_ws, size_t ws_size,
                              hipStream_t stream) {
  (void)in_sizes; (void)n_in; (void)out_size; (void)ws_size;
  const float* x   = (const float*)d_in[0];
  const float* W1  = (const float*)d_in[1];
  const float* bW1 = (const float*)d_in[2];
  const float* U1  = (const float*)d_in[3];
  const float* bU1 = (const float*)d_in[4];
  const float* W2  = (const float*)d_in[5];
  const float* bW2 = (const float*)d_in[6];
  const float* U2  = (const float*)d_in[7];
  const float* bU2 = (const float*)d_in[8];
  const float* lw  = (const float*)d_in[9];
  const float* lb  = (const float*)d_in[10];
  // d_in[11] = future (==16), compile-time constant here

  float* out = (float*)d_out;
  float* ws  = (float*)d_ws;

  const int nzero = 16 + 4 * HID * B;  // barrier counter + h1/h2 double buffers
  zero_ws<<<(nzero + TPB - 1) / TPB, TPB, 0, stream>>>(ws, nzero);
  rnn_persist<<<NWG, TPB, 0, stream>>>(x, W1, bW1, U1, bU1,
                                       W2, bW2, U2, bU2, lw, lb, out, ws);
}

// Round 2
// 30610.660 us; speedup vs baseline: 1.4836x; 1.4836x over previous
//
#include <hip/hip_runtime.h>
#include <math.h>

#define HID 512
#define B 64
#define SEQT 1024
#define FUT 16
#define TT (SEQT + FUT)
#define NWG 256
#define TPB 512
#define NWAVE 8          // TPB/64
#define JPW 2            // hidden units owned per WG = HID/NWG
#define HB (HID * B)     // one h buffer, floats
#define BLOBF 12288      // floats per WG: 4096 (phase1) + 8192 (phase2)

// ws float layout (main path):
//   [0..15]                cnt (barrier counter, int at 0)
//   [16 .. 16+2HB)         h1 double buffer
//   [.. +2HB)              h2 double buffer
//   [.. +NWG*BLOBF)        rearranged weight blobs (per WG)
//   [.. +SEQT*B)           xT (x transposed to [t][b])
#define WS_ZERO_F (16 + 4 * HB)
#define WS_BLOB_F (WS_ZERO_F)
#define WS_XT_F   (WS_BLOB_F + NWG * BLOBF)
#define WS_TOT_F  (WS_XT_F + SEQT * B)

// ---------------- grid barrier (device-scope, monotonic counter) -------------
__device__ inline void gbar(int* cnt, int target) {
  __syncthreads();
  if (threadIdx.x == 0) {
    __threadfence();  // make h writes visible device-wide before arrival
    __hip_atomic_fetch_add(cnt, 1, __ATOMIC_RELEASE, __HIP_MEMORY_SCOPE_AGENT);
    while (__hip_atomic_load(cnt, __ATOMIC_ACQUIRE, __HIP_MEMORY_SCOPE_AGENT) < target) {
      __builtin_amdgcn_s_sleep(2);
    }
  }
  __syncthreads();
}

// ---------------- prep: zero state, rearrange weights, transpose x -----------
__global__ void __launch_bounds__(256) prep_ws(
    const float* __restrict__ x,
    const float* __restrict__ U1, const float* __restrict__ W2,
    const float* __restrict__ U2, float* __restrict__ ws)
{
  const int idx = blockIdx.x * blockDim.x + threadIdx.x;
  if (idx < WS_ZERO_F) {                       // barrier counter + h buffers
    ws[idx] = 0.0f;
  }
  // weight blob: per WG wg, blob[0..4095]=phase1 [k][r], blob[4096..]=phase2 [k][rr]
  {
    const int i2 = idx - WS_ZERO_F;
    if (i2 >= 0 && i2 < NWG * BLOBF) {
      const int wg  = i2 / BLOBF;
      const int off = i2 - wg * BLOBF;
      const int j0  = wg * JPW;
      float v;
      if (off < 4096) {                        // phase1: [k*8 + r] = U1[row(r)][k]
        const int k = off >> 3, r = off & 7;
        const int row = (r >> 1) * HID + j0 + (r & 1);
        v = U1[(size_t)row * HID + k];
      } else {                                 // phase2: [k*16 + rr]
        const int o2 = off - 4096;
        const int k = o2 >> 4, rr = o2 & 15;
        const int r = rr & 7;
        const int row = (r >> 1) * HID + j0 + (r & 1);
        v = (rr < 8) ? W2[(size_t)row * HID + k] : U2[(size_t)row * HID + k];
      }
      ws[WS_BLOB_F + i2] = v;
    }
  }
  // xT[t*B + b] = x[b*SEQT + t]
  {
    const int i3 = idx - WS_XT_F;
    if (i3 >= 0 && i3 < SEQT * B) {
      const int t = i3 >> 6, b = i3 & 63;
      ws[WS_XT_F + i3] = x[(size_t)b * SEQT + t];
    }
  }
}

// ---------------- persistent 2-layer LSTM, SGPR-weight main loop -------------
__global__ void __launch_bounds__(TPB, 1) rnn_main(
    const float* __restrict__ W1, const float* __restrict__ bW1,
    const float* __restrict__ bU1,
    const float* __restrict__ bW2, const float* __restrict__ bU2,
    const float* __restrict__ lw, const float* __restrict__ lb,
    float* __restrict__ out,
    int* __restrict__ cnt,
    float* __restrict__ h1b, float* __restrict__ h2b,
    const float* __restrict__ wbl, const float* __restrict__ xT)
{
  __shared__ float red[NWAVE][8][B];   // per-wave partial dots, 16 KB
  __shared__ float outred[NWAVE][B];   // WG0 output-head reduction, 2 KB
  __shared__ float c1s[JPW][B], c2s[JPW][B];
  __shared__ float w1c[8], bs1[8], bs2[8];

  const int wg   = blockIdx.x;
  const int j0   = wg * JPW;
  const int tid  = threadIdx.x;
  const int lane = tid & 63;
  const int wvu  = __builtin_amdgcn_readfirstlane(tid >> 6);
  const int kb   = wvu << 6;  // this wave's 64-wide k-chunk

  if (tid < JPW * B) { c1s[tid >> 6][lane] = 0.f; c2s[tid >> 6][lane] = 0.f; }
  if (tid < 8) {
    const int g = tid >> 1, jl = tid & 1;
    const int row = g * HID + j0 + jl;
    w1c[tid] = W1[row];
    bs1[tid] = bW1[row] + bU1[row];
    bs2[tid] = bW2[row] + bU2[row];
  }
  __syncthreads();

  // this wave's contiguous weight regions
  const float* wp1 = wbl + (size_t)wg * BLOBF + (size_t)wvu * 512;
  const float* wp2 = wbl + (size_t)wg * BLOBF + 4096 + (size_t)wvu * 1024;
  const float lbv = lb[0];

  int bar = 0;
  for (int t = 0; t < TT; ++t) {
    const float* h1old = h1b + ((t + 1) & 1) * HB;
    float*       h1new = h1b + (t & 1) * HB;
    const float* h2old = h2b + ((t + 1) & 1) * HB;
    float*       h2new = h2b + (t & 1) * HB;

    // -------- phase 1: gates1 = U1 h1(t-1)  (x*W1 + b added in cell) --------
    {
      const float* hp = h1old + (size_t)kb * B;
      float a[8] = {0.f,0.f,0.f,0.f,0.f,0.f,0.f,0.f};
      for (int c = 0; c < 8; ++c) {          // 8 chunks of 8 k
        float w[64];
        #pragma unroll
        for (int i = 0; i < 64; ++i) w[i] = wp1[c * 64 + i];
        #pragma unroll
        for (int j = 0; j < 8; ++j) {
          const float hv = hp[(c * 8 + j) * B + lane];
          #pragma unroll
          for (int r = 0; r < 8; ++r) a[r] = fmaf(w[j * 8 + r], hv, a[r]);
        }
      }
      #pragma unroll
      for (int r = 0; r < 8; ++r) red[wvu][r][lane] = a[r];
    }
    __syncthreads();

    // cell-1 elementwise (2 j's x 64 b = 128 threads)
    if (tid < JPW * B) {
      const int jl = tid >> 6, b = tid & 63;
      const float xv = (t < SEQT) ? xT[(size_t)t * B + b]
                                  : out[(size_t)b * TT + (t - 1)];
      float gate[4];
      #pragma unroll
      for (int g = 0; g < 4; ++g) {
        const int r = g * 2 + jl;
        float s = bs1[r] + xv * w1c[r];
        #pragma unroll
        for (int w = 0; w < NWAVE; ++w) s += red[w][r][b];
        gate[g] = s;
      }
      const float c = gate[1] * c1s[jl][b] + gate[0] * gate[2];
      c1s[jl][b] = c;
      h1new[(size_t)(j0 + jl) * B + b] = gate[3] * tanhf(c);
    }

    ++bar;
    gbar(cnt, NWG * bar);

    // WG0: output head for step t-1 (teacher region), overlapped with phase 2
    if (wg == 0 && t >= 1 && t <= SEQT - 1) {
      const float* hb2 = h2old + (size_t)(wvu * 64) * B;
      const float* lwp = lw + wvu * 64;
      float p = 0.f;
      #pragma unroll 8
      for (int j = 0; j < 64; ++j) p = fmaf(lwp[j], hb2[j * B + lane], p);
      outred[wvu][lane] = p;
      __syncthreads();
      if (tid < B) {
        float o = lbv;
        #pragma unroll
        for (int s = 0; s < NWAVE; ++s) o += outred[s][tid];
        out[(size_t)tid * TT + (t - 1)] = o;
      }
      __syncthreads();
    }

    // -------- phase 2: gates2 = W2 h1(t) + U2 h2(t-1) ------------------------
    {
      const float* h1p = h1new + (size_t)kb * B;
      const float* h2p = h2old + (size_t)kb * B;
      float a[8] = {0.f,0.f,0.f,0.f,0.f,0.f,0.f,0.f};
      for (int c = 0; c < 16; ++c) {         // 16 chunks of 4 k
        float w[64];
        #pragma unroll
        for (int i = 0; i < 64; ++i) w[i] = wp2[c * 64 + i];
        #pragma unroll
        for (int j = 0; j < 4; ++j) {
          const float h1v = h1p[(c * 4 + j) * B + lane];
          const float h2v = h2p[(c * 4 + j) * B + lane];
          #pragma unroll
          for (int r = 0; r < 8; ++r) a[r] = fmaf(w[j * 16 + r], h1v, a[r]);
          #pragma unroll
          for (int r = 0; r < 8; ++r) a[r] = fmaf(w[j * 16 + 8 + r], h2v, a[r]);
        }
      }
      #pragma unroll
      for (int r = 0; r < 8; ++r) red[wvu][r][lane] = a[r];
    }
    __syncthreads();

    // cell-2 elementwise
    if (tid < JPW * B) {
      const int jl = tid >> 6, b = tid & 63;
      float gate[4];
      #pragma unroll
      for (int g = 0; g < 4; ++g) {
        const int r = g * 2 + jl;
        float s = bs2[r];
        #pragma unroll
        for (int w = 0; w < NWAVE; ++w) s += red[w][r][b];
        gate[g] = s;
      }
      const float c = gate[1] * c2s[jl][b] + gate[0] * gate[2];
      c2s[jl][b] = c;
      h2new[(size_t)(j0 + jl) * B + b] = gate[3] * tanhf(c);
    }
    __syncthreads();  // protect red[] before next step's phase-1 writes

    // Autoregressive region: out(t) must be globally visible before phase1(t+1)
    if (t >= SEQT - 1) {
      ++bar;
      gbar(cnt, NWG * bar);
      if (wg == 0) {
        const float* hb2 = h2new + (size_t)(wvu * 64) * B;
        const float* lwp = lw + wvu * 64;
        float p = 0.f;
        #pragma unroll 8
        for (int j = 0; j < 64; ++j) p = fmaf(lwp[j], hb2[j * B + lane], p);
        outred[wvu][lane] = p;
        __syncthreads();
        if (tid < B) {
          float o = lbv;
          #pragma unroll
          for (int s = 0; s < NWAVE; ++s) o += outred[s][tid];
          out[(size_t)tid * TT + t] = o;
        }
        __syncthreads();
      }
      ++bar;
      gbar(cnt, NWG * bar);
    }
  }
}

// =================== fallback path (round-0 kernel, known correct) ===========
__global__ void __launch_bounds__(TPB) zero_ws(float* ws, int n) {
  int i = blockIdx.x * blockDim.x + threadIdx.x;
  if (i < n) ws[i] = 0.0f;
}

__global__ void __launch_bounds__(TPB) rnn_fallback(
    const float* __restrict__ x,
    const float* __restrict__ W1, const float* __restrict__ bW1,
    const float* __restrict__ U1, const float* __restrict__ bU1,
    const float* __restrict__ W2, const float* __restrict__ bW2,
    const float* __restrict__ U2, const float* __restrict__ bU2,
    const float* __restrict__ lw, const float* __restrict__ lb,
    float* out, float* ws)
{
  __shared__ float red[NWAVE][8][B];
  __shared__ float outred[NWAVE][B];
  __shared__ float c1s[JPW][B], c2s[JPW][B];
  __shared__ float w1c[8], bs1[8], bs2[8];

  int* cnt   = (int*)ws;
  float* h1b = ws + 16;
  float* h2b = h1b + 2 * HB;

  const int wg   = blockIdx.x;
  const int j0   = wg * JPW;
  const int tid  = threadIdx.x;
  const int lane = tid & 63;
  const int wvu  = __builtin_amdgcn_readfirstlane(tid >> 6);
  const int kb   = wvu << 6;

  if (tid < JPW * B) { c1s[tid >> 6][lane] = 0.f; c2s[tid >> 6][lane] = 0.f; }
  if (tid < 8) {
    const int g = tid >> 1, jl = tid & 1;
    const int row = g * HID + j0 + jl;
    w1c[tid] = W1[row];
    bs1[tid] = bW1[row] + bU1[row];
    bs2[tid] = bW2[row] + bU2[row];
  }
  __syncthreads();

  const float* u1p[8]; const float* w2p[8]; const float* u2p[8];
  #pragma unroll
  for (int r = 0; r < 8; ++r) {
    const int row = (r >> 1) * HID + j0 + (r & 1);
    u1p[r] = U1 + (size_t)row * HID + kb;
    w2p[r] = W2 + (size_t)row * HID + kb;
    u2p[r] = U2 + (size_t)row * HID + kb;
  }
  const float lbv = lb[0];

  int bar = 0;
  for (int t = 0; t < TT; ++t) {
    const float* h1old = h1b + ((t + 1) & 1) * HB;
    float*       h1new = h1b + (t & 1) * HB;
    const float* h2old = h2b + ((t + 1) & 1) * HB;
    float*       h2new = h2b + (t & 1) * HB;

    {
      const float* hp = h1old + (size_t)kb * B;
      float a0=0.f,a1=0.f,a2=0.f,a3=0.f,a4=0.f,a5=0.f,a6=0.f,a7=0.f;
      #pragma unroll 8
      for (int k = 0; k < 64; ++k) {
        const float hv = hp[k * B + lane];
        a0 = fmaf(u1p[0][k], hv, a0); a1 = fmaf(u1p[1][k], hv, a1);
        a2 = fmaf(u1p[2][k], hv, a2); a3 = fmaf(u1p[3][k], hv, a3);
        a4 = fmaf(u1p[4][k], hv, a4); a5 = fmaf(u1p[5][k], hv, a5);
        a6 = fmaf(u1p[6][k], hv, a6); a7 = fmaf(u1p[7][k], hv, a7);
      }
      red[wvu][0][lane]=a0; red[wvu][1][lane]=a1; red[wvu][2][lane]=a2; red[wvu][3][lane]=a3;
      red[wvu][4][lane]=a4; red[wvu][5][lane]=a5; red[wvu][6][lane]=a6; red[wvu][7][lane]=a7;
    }
    __syncthreads();

    if (tid < JPW * B) {
      const int jl = tid >> 6, b = tid & 63;
      const float xv = (t < SEQT) ? x[(size_t)b * SEQT + t]
                                  : out[(size_t)b * TT + (t - 1)];
      float gate[4];
      #pragma unroll
      for (int g = 0; g < 4; ++g) {
        const int r = g * 2 + jl;
        float s = bs1[r] + xv * w1c[r];
        #pragma unroll
        for (int w = 0; w < NWAVE; ++w) s += red[w][r][b];
        gate[g] = s;
      }
      const float c = gate[1] * c1s[jl][b] + gate[0] * gate[2];
      c1s[jl][b] = c;
      h1new[(size_t)(j0 + jl) * B + b] = gate[3] * tanhf(c);
    }

    ++bar;
    gbar(cnt, NWG * bar);

    if (wg == 0 && t >= 1 && t <= SEQT - 1) {
      const float* hb2 = h2old + (size_t)(wvu * 64) * B;
      const float* lwp = lw + wvu * 64;
      float p = 0.f;
      #pragma unroll 8
      for (int j = 0; j < 64; ++j) p = fmaf(lwp[j], hb2[j * B + lane], p);
      outred[wvu][lane] = p;
      __syncthreads();
      if (tid < B) {
        float o = lbv;
        #pragma unroll
        for (int s = 0; s < NWAVE; ++s) o += outred[s][tid];
        out[(size_t)tid * TT + (t - 1)] = o;
      }
      __syncthreads();
    }

    {
      const float* h1p = h1new + (size_t)kb * B;
      const float* h2p = h2old + (size_t)kb * B;
      float s0=0.f,s1=0.f,s2=0.f,s3=0.f,s4=0.f,s5=0.f,s6=0.f,s7=0.f;
      float q0=0.f,q1=0.f,q2=0.f,q3=0.f,q4=0.f,q5=0.f,q6=0.f,q7=0.f;
      #pragma unroll 4
      for (int k = 0; k < 64; ++k) {
        const float h1v = h1p[k * B + lane];
        const float h2v = h2p[k * B + lane];
        s0 = fmaf(w2p[0][k], h1v, s0); q0 = fmaf(u2p[0][k], h2v, q0);
        s1 = fmaf(w2p[1][k], h1v, s1); q1 = fmaf(u2p[1][k], h2v, q1);
        s2 = fmaf(w2p[2][k], h1v, s2); q2 = fmaf(u2p[2][k], h2v, q2);
        s3 = fmaf(w2p[3][k], h1v, s3); q3 = fmaf(u2p[3][k], h2v, q3);
        s4 = fmaf(w2p[4][k], h1v, s4); q4 = fmaf(u2p[4][k], h2v, q4);
        s5 = fmaf(w2p[5][k], h1v, s5); q5 = fmaf(u2p[5][k], h2v, q5);
        s6 = fmaf(w2p[6][k], h1v, s6); q6 = fmaf(u2p[6][k], h2v, q6);
        s7 = fmaf(w2p[7][k], h1v, s7); q7 = fmaf(u2p[7][k], h2v, q7);
      }
      red[wvu][0][lane]=s0+q0; red[wvu][1][lane]=s1+q1;
      red[wvu][2][lane]=s2+q2; red[wvu][3][lane]=s3+q3;
      red[wvu][4][lane]=s4+q4; red[wvu][5][lane]=s5+q5;
      red[wvu][6][lane]=s6+q6; red[wvu][7][lane]=s7+q7;
    }
    __syncthreads();

    if (tid < JPW * B) {
      const int jl = tid >> 6, b = tid & 63;
      float gate[4];
      #pragma unroll
      for (int g = 0; g < 4; ++g) {
        const int r = g * 2 + jl;
        float s = bs2[r];
        #pragma unroll
        for (int w = 0; w < NWAVE; ++w) s += red[w][r][b];
        gate[g] = s;
      }
      const float c = gate[1] * c2s[jl][b] + gate[0] * gate[2];
      c2s[jl][b] = c;
      h2new[(size_t)(j0 + jl) * B + b] = gate[3] * tanhf(c);
    }
    __syncthreads();

    if (t >= SEQT - 1) {
      ++bar;
      gbar(cnt, NWG * bar);
      if (wg == 0) {
        const float* hb2 = h2new + (size_t)(wvu * 64) * B;
        const float* lwp = lw + wvu * 64;
        float p = 0.f;
        #pragma unroll 8
        for (int j = 0; j < 64; ++j) p = fmaf(lwp[j], hb2[j * B + lane], p);
        outred[wvu][lane] = p;
        __syncthreads();
        if (tid < B) {
          float o = lbv;
          #pragma unroll
          for (int s = 0; s < NWAVE; ++s) o += outred[s][tid];
          out[(size_t)tid * TT + t] = o;
        }
        __syncthreads();
      }
      ++bar;
      gbar(cnt, NWG * bar);
    }
  }
}

extern "C" void kernel_launch(void* const* d_in, const int* in_sizes, int n_in,
                              void* d_out, int out_size, void* d_ws, size_t ws_size,
                              hipStream_t stream) {
  (void)in_sizes; (void)n_in; (void)out_size;
  const float* x   = (const float*)d_in[0];
  const float* W1  = (const float*)d_in[1];
  const float* bW1 = (const float*)d_in[2];
  const float* U1  = (const float*)d_in[3];
  const float* bU1 = (const float*)d_in[4];
  const float* W2  = (const float*)d_in[5];
  const float* bW2 = (const float*)d_in[6];
  const float* U2  = (const float*)d_in[7];
  const float* bU2 = (const float*)d_in[8];
  const float* lw  = (const float*)d_in[9];
  const float* lb  = (const float*)d_in[10];

  float* out = (float*)d_out;
  float* ws  = (float*)d_ws;

  if (ws_size >= (size_t)WS_TOT_F * sizeof(float)) {
    const int nprep = WS_TOT_F;
    prep_ws<<<(nprep + 255) / 256, 256, 0, stream>>>(x, U1, W2, U2, ws);
    rnn_main<<<NWG, TPB, 0, stream>>>(W1, bW1, bU1, bW2, bU2, lw, lb, out,
                                      (int*)ws, ws + 16, ws + 16 + 2 * HB,
                                      ws + WS_BLOB_F, ws + WS_XT_F);
  } else {
    const int nzero = 16 + 4 * HID * B;
    zero_ws<<<(nzero + TPB - 1) / TPB, TPB, 0, stream>>>(ws, nzero);
    rnn_fallback<<<NWG, TPB, 0, stream>>>(x, W1, bW1, U1, bU1,
                                          W2, bW2, U2, bU2, lw, lb, out, ws);
  }
}

// Round 3
// 27988.177 us; speedup vs baseline: 1.6227x; 1.0937x over previous
//
#include <hip/hip_runtime.h>
#include <math.h>

#define HID 512
#define B 64
#define SEQT 1024
#define FUT 16
#define TT (SEQT + FUT)
#define NWG 256
#define TPB 512
#define NWAVE 8          // TPB/64
#define JPW 2            // hidden units owned per WG = HID/NWG
#define HB (HID * B)     // one h buffer, floats
#define BLOBF 12288      // floats per WG: 4096 (phase1) + 8192 (phase2)

// ws float layout (main path):
//   [0..511]               barrier block (ints): grp[g] at int g*32 (g<8),
//                          root at int 256, go at int 288
//   [512 .. +2HB)          h1 double buffer  (float4 tiles: h4[k>>2][b][k&3])
//   [.. +2HB)              h2 double buffer  (same layout)
//   [.. +NWG*BLOBF)        rearranged weight blobs (per WG)
//   [.. +SEQT*B)           xT (x transposed to [t][b])
#define WS_H1_F   512
#define WS_H2_F   (WS_H1_F + 2 * HB)
#define WS_BLOB_F (WS_H2_F + 2 * HB)
#define WS_XT_F   (WS_BLOB_F + NWG * BLOBF)
#define WS_TOT_F  (WS_XT_F + SEQT * B)

// -------- hierarchical grid barrier: 8 group counters -> root -> go flag -----
__device__ inline void gbar2(int* bb, int wg, int bar) {
  __syncthreads();
  if (threadIdx.x == 0) {
    __threadfence();  // release: flush this WG's h writes toward LIC
    const int g = wg & 7;
    int old = __hip_atomic_fetch_add(bb + g * 32, 1, __ATOMIC_RELAXED,
                                     __HIP_MEMORY_SCOPE_AGENT);
    if (old == 32 * bar - 1) {          // last arrival in group
      int r = __hip_atomic_fetch_add(bb + 256, 1, __ATOMIC_RELAXED,
                                     __HIP_MEMORY_SCOPE_AGENT);
      if (r == 8 * bar - 1) {           // last group
        __hip_atomic_store(bb + 288, bar, __ATOMIC_RELEASE,
                           __HIP_MEMORY_SCOPE_AGENT);
      }
    }
    while (__hip_atomic_load(bb + 288, __ATOMIC_ACQUIRE,
                             __HIP_MEMORY_SCOPE_AGENT) < bar) {
      __builtin_amdgcn_s_sleep(2);
    }
  }
  __syncthreads();
}

// ---------------- prep: zero state, rearrange weights, transpose x -----------
__global__ void __launch_bounds__(256) prep_ws(
    const float* __restrict__ x,
    const float* __restrict__ U1, const float* __restrict__ W2,
    const float* __restrict__ U2, float* __restrict__ ws)
{
  const int idx = blockIdx.x * blockDim.x + threadIdx.x;
  if (idx < WS_BLOB_F) {                       // barrier block + h buffers
    ws[idx] = 0.0f;
  }
  {
    const int i2 = idx - WS_BLOB_F;
    if (i2 >= 0 && i2 < NWG * BLOBF) {
      const int wg  = i2 / BLOBF;
      const int off = i2 - wg * BLOBF;
      const int j0  = wg * JPW;
      float v;
      if (off < 4096) {                        // phase1: [k*8 + r] = U1[row(r)][k]
        const int k = off >> 3, r = off & 7;
        const int row = (r >> 1) * HID + j0 + (r & 1);
        v = U1[(size_t)row * HID + k];
      } else {                                 // phase2: [k*16 + rr]
        const int o2 = off - 4096;
        const int k = o2 >> 4, rr = o2 & 15;
        const int r = rr & 7;
        const int row = (r >> 1) * HID + j0 + (r & 1);
        v = (rr < 8) ? W2[(size_t)row * HID + k] : U2[(size_t)row * HID + k];
      }
      ws[WS_BLOB_F + i2] = v;
    }
  }
  {
    const int i3 = idx - WS_XT_F;
    if (i3 >= 0 && i3 < SEQT * B) {
      const int t = i3 >> 6, b = i3 & 63;
      ws[WS_XT_F + i3] = x[(size_t)b * SEQT + t];
    }
  }
}

// ---------------- persistent 2-layer LSTM: LDS weights, float4 h -------------
__global__ void __launch_bounds__(TPB, 1) rnn_main(
    const float* __restrict__ W1, const float* __restrict__ bW1,
    const float* __restrict__ bU1,
    const float* __restrict__ bW2, const float* __restrict__ bU2,
    const float* __restrict__ lw, const float* __restrict__ lb,
    float* __restrict__ out,
    int* __restrict__ bb,
    float* __restrict__ h1b, float* __restrict__ h2b,
    const float* __restrict__ wbl, const float* __restrict__ xT)
{
  __shared__ float wlds[BLOBF];        // 48 KB persistent weight blob
  __shared__ float red[NWAVE][8][B];   // per-wave partial dots, 16 KB
  __shared__ float outred[NWAVE][B];   // WG0 output-head reduction, 2 KB
  __shared__ float c1s[JPW][B], c2s[JPW][B];
  __shared__ float w1c[8], bs1[8], bs2[8];

  const int wg   = blockIdx.x;
  const int j0   = wg * JPW;
  const int tid  = threadIdx.x;
  const int lane = tid & 63;
  const int wvu  = __builtin_amdgcn_readfirstlane(tid >> 6);

  // ---- one-time: copy this WG's weight blob into LDS ----
  {
    const float4* gsrc = (const float4*)(wbl + (size_t)wg * BLOBF);
    float4* ldst = (float4*)wlds;
    #pragma unroll
    for (int i = 0; i < BLOBF / 4 / TPB; ++i)
      ldst[i * TPB + tid] = gsrc[i * TPB + tid];
  }
  if (tid < JPW * B) { c1s[tid >> 6][lane] = 0.f; c2s[tid >> 6][lane] = 0.f; }
  if (tid < 8) {
    const int g = tid >> 1, jl = tid & 1;
    const int row = g * HID + j0 + jl;
    w1c[tid] = W1[row];
    bs1[tid] = bW1[row] + bU1[row];
    bs2[tid] = bW2[row] + bU2[row];
  }
  __syncthreads();

  const float* wl1 = wlds + wvu * 512;          // phase1 weights, this wave
  const float* wl2 = wlds + 4096 + wvu * 1024;  // phase2 weights, this wave
  const float lbv = lb[0];

  int bar = 0;
  for (int t = 0; t < TT; ++t) {
    const float* h1old = h1b + ((t + 1) & 1) * HB;
    float*       h1new = h1b + (t & 1) * HB;
    const float* h2old = h2b + ((t + 1) & 1) * HB;
    float*       h2new = h2b + (t & 1) * HB;

    // prefetch x for cell-1 (teacher region)
    float xvpref = 0.f;
    if (tid < JPW * B && t < SEQT) xvpref = xT[(size_t)t * B + lane];

    // -------- phase 1: gates1 = U1 h1(t-1) ----------------------------------
    {
      const float4* hp = (const float4*)h1old + (size_t)(wvu * 16) * B + lane;
      float4 hq[16];
      #pragma unroll
      for (int i = 0; i < 16; ++i) hq[i] = hp[i * B];
      float a[8] = {0.f,0.f,0.f,0.f,0.f,0.f,0.f,0.f};
      #pragma unroll
      for (int c = 0; c < 16; ++c) {            // k-quad within this wave's 64-k
        const float hh[4] = {hq[c].x, hq[c].y, hq[c].z, hq[c].w};
        #pragma unroll
        for (int j = 0; j < 4; ++j) {
          const float4 wA = *(const float4*)(wl1 + c * 32 + j * 8);
          const float4 wB = *(const float4*)(wl1 + c * 32 + j * 8 + 4);
          const float h = hh[j];
          a[0] = fmaf(wA.x, h, a[0]); a[1] = fmaf(wA.y, h, a[1]);
          a[2] = fmaf(wA.z, h, a[2]); a[3] = fmaf(wA.w, h, a[3]);
          a[4] = fmaf(wB.x, h, a[4]); a[5] = fmaf(wB.y, h, a[5]);
          a[6] = fmaf(wB.z, h, a[6]); a[7] = fmaf(wB.w, h, a[7]);
        }
      }
      #pragma unroll
      for (int r = 0; r < 8; ++r) red[wvu][r][lane] = a[r];
    }
    __syncthreads();

    // cell-1 elementwise (2 j's x 64 b = 128 threads)
    if (tid < JPW * B) {
      const int jl = tid >> 6, b = tid & 63;
      const float xv = (t < SEQT) ? xvpref : out[(size_t)b * TT + (t - 1)];
      float gate[4];
      #pragma unroll
      for (int g = 0; g < 4; ++g) {
        const int r = g * 2 + jl;
        float s = bs1[r] + xv * w1c[r];
        #pragma unroll
        for (int w = 0; w < NWAVE; ++w) s += red[w][r][b];
        gate[g] = s;
      }
      const float c = gate[1] * c1s[jl][b] + gate[0] * gate[2];
      c1s[jl][b] = c;
      const int j = j0 + jl;
      h1new[(size_t)(j >> 2) * (B * 4) + b * 4 + (j & 3)] = gate[3] * tanhf(c);
    }

    ++bar;
    gbar2(bb, wg, bar);

    // WG0: output head for step t-1 (teacher region), overlapped with phase 2
    if (wg == 0 && t >= 1 && t <= SEQT - 1) {
      const float4* hb2 = (const float4*)h2old + (size_t)(wvu * 16) * B + lane;
      const float4* lw4 = (const float4*)lw + wvu * 16;
      float p = 0.f;
      #pragma unroll
      for (int i = 0; i < 16; ++i) {
        const float4 hv = hb2[i * B];
        const float4 wv = lw4[i];
        p = fmaf(wv.x, hv.x, p); p = fmaf(wv.y, hv.y, p);
        p = fmaf(wv.z, hv.z, p); p = fmaf(wv.w, hv.w, p);
      }
      outred[wvu][lane] = p;
      __syncthreads();
      if (tid < B) {
        float o = lbv;
        #pragma unroll
        for (int s = 0; s < NWAVE; ++s) o += outred[s][tid];
        out[(size_t)tid * TT + (t - 1)] = o;
      }
      __syncthreads();
    }

    // -------- phase 2: gates2 = W2 h1(t) + U2 h2(t-1) ------------------------
    {
      const float4* pp4 = (const float4*)h1new + (size_t)(wvu * 16) * B + lane;
      const float4* qq4 = (const float4*)h2old + (size_t)(wvu * 16) * B + lane;
      float4 P[16], Q[16];
      #pragma unroll
      for (int i = 0; i < 16; ++i) P[i] = pp4[i * B];
      #pragma unroll
      for (int i = 0; i < 16; ++i) Q[i] = qq4[i * B];
      float a[8] = {0.f,0.f,0.f,0.f,0.f,0.f,0.f,0.f};
      #pragma unroll
      for (int c = 0; c < 16; ++c) {
        const float hp_[4] = {P[c].x, P[c].y, P[c].z, P[c].w};
        const float hq_[4] = {Q[c].x, Q[c].y, Q[c].z, Q[c].w};
        #pragma unroll
        for (int j = 0; j < 4; ++j) {
          const float4 w0 = *(const float4*)(wl2 + c * 64 + j * 16);
          const float4 w1 = *(const float4*)(wl2 + c * 64 + j * 16 + 4);
          const float4 w2 = *(const float4*)(wl2 + c * 64 + j * 16 + 8);
          const float4 w3 = *(const float4*)(wl2 + c * 64 + j * 16 + 12);
          const float hp1 = hp_[j], hq1 = hq_[j];
          a[0] = fmaf(w0.x, hp1, a[0]); a[1] = fmaf(w0.y, hp1, a[1]);
          a[2] = fmaf(w0.z, hp1, a[2]); a[3] = fmaf(w0.w, hp1, a[3]);
          a[4] = fmaf(w1.x, hp1, a[4]); a[5] = fmaf(w1.y, hp1, a[5]);
          a[6] = fmaf(w1.z, hp1, a[6]); a[7] = fmaf(w1.w, hp1, a[7]);
          a[0] = fmaf(w2.x, hq1, a[0]); a[1] = fmaf(w2.y, hq1, a[1]);
          a[2] = fmaf(w2.z, hq1, a[2]); a[3] = fmaf(w2.w, hq1, a[3]);
          a[4] = fmaf(w3.x, hq1, a[4]); a[5] = fmaf(w3.y, hq1, a[5]);
          a[6] = fmaf(w3.z, hq1, a[6]); a[7] = fmaf(w3.w, hq1, a[7]);
        }
      }
      #pragma unroll
      for (int r = 0; r < 8; ++r) red[wvu][r][lane] = a[r];
    }
    __syncthreads();

    // cell-2 elementwise
    if (tid < JPW * B) {
      const int jl = tid >> 6, b = tid & 63;
      float gate[4];
      #pragma unroll
      for (int g = 0; g < 4; ++g) {
        const int r = g * 2 + jl;
        float s = bs2[r];
        #pragma unroll
        for (int w = 0; w < NWAVE; ++w) s += red[w][r][b];
        gate[g] = s;
      }
      const float c = gate[1] * c2s[jl][b] + gate[0] * gate[2];
      c2s[jl][b] = c;
      const int j = j0 + jl;
      h2new[(size_t)(j >> 2) * (B * 4) + b * 4 + (j & 3)] = gate[3] * tanhf(c);
    }
    __syncthreads();  // protect red[] before next step's phase-1 writes

    // Autoregressive region: out(t) must be globally visible before phase1(t+1)
    if (t >= SEQT - 1) {
      ++bar;
      gbar2(bb, wg, bar);
      if (wg == 0) {
        const float4* hb2 = (const float4*)h2new + (size_t)(wvu * 16) * B + lane;
        const float4* lw4 = (const float4*)lw + wvu * 16;
        float p = 0.f;
        #pragma unroll
        for (int i = 0; i < 16; ++i) {
          const float4 hv = hb2[i * B];
          const float4 wv = lw4[i];
          p = fmaf(wv.x, hv.x, p); p = fmaf(wv.y, hv.y, p);
          p = fmaf(wv.z, hv.z, p); p = fmaf(wv.w, hv.w, p);
        }
        outred[wvu][lane] = p;
        __syncthreads();
        if (tid < B) {
          float o = lbv;
          #pragma unroll
          for (int s = 0; s < NWAVE; ++s) o += outred[s][tid];
          out[(size_t)tid * TT + t] = o;
        }
        __syncthreads();
      }
      ++bar;
      gbar2(bb, wg, bar);
    }
  }
}

// =================== fallback path (round-0 kernel, known correct) ===========
__device__ inline void gbar(int* cnt, int target) {
  __syncthreads();
  if (threadIdx.x == 0) {
    __threadfence();
    __hip_atomic_fetch_add(cnt, 1, __ATOMIC_RELEASE, __HIP_MEMORY_SCOPE_AGENT);
    while (__hip_atomic_load(cnt, __ATOMIC_ACQUIRE, __HIP_MEMORY_SCOPE_AGENT) < target) {
      __builtin_amdgcn_s_sleep(2);
    }
  }
  __syncthreads();
}

__global__ void __launch_bounds__(TPB) zero_ws(float* ws, int n) {
  int i = blockIdx.x * blockDim.x + threadIdx.x;
  if (i < n) ws[i] = 0.0f;
}

__global__ void __launch_bounds__(TPB) rnn_fallback(
    const float* __restrict__ x,
    const float* __restrict__ W1, const float* __restrict__ bW1,
    const float* __restrict__ U1, const float* __restrict__ bU1,
    const float* __restrict__ W2, const float* __restrict__ bW2,
    const float* __restrict__ U2, const float* __restrict__ bU2,
    const float* __restrict__ lw, const float* __restrict__ lb,
    float* out, float* ws)
{
  __shared__ float red[NWAVE][8][B];
  __shared__ float outred[NWAVE][B];
  __shared__ float c1s[JPW][B], c2s[JPW][B];
  __shared__ float w1c[8], bs1[8], bs2[8];

  int* cnt   = (int*)ws;
  float* h1b = ws + 16;
  float* h2b = h1b + 2 * HB;

  const int wg   = blockIdx.x;
  const int j0   = wg * JPW;
  const int tid  = threadIdx.x;
  const int lane = tid & 63;
  const int wvu  = __builtin_amdgcn_readfirstlane(tid >> 6);
  const int kb   = wvu << 6;

  if (tid < JPW * B) { c1s[tid >> 6][lane] = 0.f; c2s[tid >> 6][lane] = 0.f; }
  if (tid < 8) {
    const int g = tid >> 1, jl = tid & 1;
    const int row = g * HID + j0 + jl;
    w1c[tid] = W1[row];
    bs1[tid] = bW1[row] + bU1[row];
    bs2[tid] = bW2[row] + bU2[row];
  }
  __syncthreads();

  const float* u1p[8]; const float* w2p[8]; const float* u2p[8];
  #pragma unroll
  for (int r = 0; r < 8; ++r) {
    const int row = (r >> 1) * HID + j0 + (r & 1);
    u1p[r] = U1 + (size_t)row * HID + kb;
    w2p[r] = W2 + (size_t)row * HID + kb;
    u2p[r] = U2 + (size_t)row * HID + kb;
  }
  const float lbv = lb[0];

  int bar = 0;
  for (int t = 0; t < TT; ++t) {
    const float* h1old = h1b + ((t + 1) & 1) * HB;
    float*       h1new = h1b + (t & 1) * HB;
    const float* h2old = h2b + ((t + 1) & 1) * HB;
    float*       h2new = h2b + (t & 1) * HB;

    {
      const float* hp = h1old + (size_t)kb * B;
      float a0=0.f,a1=0.f,a2=0.f,a3=0.f,a4=0.f,a5=0.f,a6=0.f,a7=0.f;
      #pragma unroll 8
      for (int k = 0; k < 64; ++k) {
        const float hv = hp[k * B + lane];
        a0 = fmaf(u1p[0][k], hv, a0); a1 = fmaf(u1p[1][k], hv, a1);
        a2 = fmaf(u1p[2][k], hv, a2); a3 = fmaf(u1p[3][k], hv, a3);
        a4 = fmaf(u1p[4][k], hv, a4); a5 = fmaf(u1p[5][k], hv, a5);
        a6 = fmaf(u1p[6][k], hv, a6); a7 = fmaf(u1p[7][k], hv, a7);
      }
      red[wvu][0][lane]=a0; red[wvu][1][lane]=a1; red[wvu][2][lane]=a2; red[wvu][3][lane]=a3;
      red[wvu][4][lane]=a4; red[wvu][5][lane]=a5; red[wvu][6][lane]=a6; red[wvu][7][lane]=a7;
    }
    __syncthreads();

    if (tid < JPW * B) {
      const int jl = tid >> 6, b = tid & 63;
      const float xv = (t < SEQT) ? x[(size_t)b * SEQT + t]
                                  : out[(size_t)b * TT + (t - 1)];
      float gate[4];
      #pragma unroll
      for (int g = 0; g < 4; ++g) {
        const int r = g * 2 + jl;
        float s = bs1[r] + xv * w1c[r];
        #pragma unroll
        for (int w = 0; w < NWAVE; ++w) s += red[w][r][b];
        gate[g] = s;
      }
      const float c = gate[1] * c1s[jl][b] + gate[0] * gate[2];
      c1s[jl][b] = c;
      h1new[(size_t)(j0 + jl) * B + b] = gate[3] * tanhf(c);
    }

    ++bar;
    gbar(cnt, NWG * bar);

    if (wg == 0 && t >= 1 && t <= SEQT - 1) {
      const float* hb2 = h2old + (size_t)(wvu * 64) * B;
      const float* lwp = lw + wvu * 64;
      float p = 0.f;
      #pragma unroll 8
      for (int j = 0; j < 64; ++j) p = fmaf(lwp[j], hb2[j * B + lane], p);
      outred[wvu][lane] = p;
      __syncthreads();
      if (tid < B) {
        float o = lbv;
        #pragma unroll
        for (int s = 0; s < NWAVE; ++s) o += outred[s][tid];
        out[(size_t)tid * TT + (t - 1)] = o;
      }
      __syncthreads();
    }

    {
      const float* h1p = h1new + (size_t)kb * B;
      const float* h2p = h2old + (size_t)kb * B;
      float s0=0.f,s1=0.f,s2=0.f,s3=0.f,s4=0.f,s5=0.f,s6=0.f,s7=0.f;
      float q0=0.f,q1=0.f,q2=0.f,q3=0.f,q4=0.f,q5=0.f,q6=0.f,q7=0.f;
      #pragma unroll 4
      for (int k = 0; k < 64; ++k) {
        const float h1v = h1p[k * B + lane];
        const float h2v = h2p[k * B + lane];
        s0 = fmaf(w2p[0][k], h1v, s0); q0 = fmaf(u2p[0][k], h2v, q0);
        s1 = fmaf(w2p[1][k], h1v, s1); q1 = fmaf(u2p[1][k], h2v, q1);
        s2 = fmaf(w2p[2][k], h1v, s2); q2 = fmaf(u2p[2][k], h2v, q2);
        s3 = fmaf(w2p[3][k], h1v, s3); q3 = fmaf(u2p[3][k], h2v, q3);
        s4 = fmaf(w2p[4][k], h1v, s4); q4 = fmaf(u2p[4][k], h2v, q4);
        s5 = fmaf(w2p[5][k], h1v, s5); q5 = fmaf(u2p[5][k], h2v, q5);
        s6 = fmaf(w2p[6][k], h1v, s6); q6 = fmaf(u2p[6][k], h2v, q6);
        s7 = fmaf(w2p[7][k], h1v, s7); q7 = fmaf(u2p[7][k], h2v, q7);
      }
      red[wvu][0][lane]=s0+q0; red[wvu][1][lane]=s1+q1;
      red[wvu][2][lane]=s2+q2; red[wvu][3][lane]=s3+q3;
      red[wvu][4][lane]=s4+q4; red[wvu][5][lane]=s5+q5;
      red[wvu][6][lane]=s6+q6; red[wvu][7][lane]=s7+q7;
    }
    __syncthreads();

    if (tid < JPW * B) {
      const int jl = tid >> 6, b = tid & 63;
      float gate[4];
      #pragma unroll
      for (int g = 0; g < 4; ++g) {
        const int r = g * 2 + jl;
        float s = bs2[r];
        #pragma unroll
        for (int w = 0; w < NWAVE; ++w) s += red[w][r][b];
        gate[g] = s;
      }
      const float c = gate[1] * c2s[jl][b] + gate[0] * gate[2];
      c2s[jl][b] = c;
      h2new[(size_t)(j0 + jl) * B + b] = gate[3] * tanhf(c);
    }
    __syncthreads();

    if (t >= SEQT - 1) {
      ++bar;
      gbar(cnt, NWG * bar);
      if (wg == 0) {
        const float* hb2 = h2new + (size_t)(wvu * 64) * B;
        const float* lwp = lw + wvu * 64;
        float p = 0.f;
        #pragma unroll 8
        for (int j = 0; j < 64; ++j) p = fmaf(lwp[j], hb2[j * B + lane], p);
        outred[wvu][lane] = p;
        __syncthreads();
        if (tid < B) {
          float o = lbv;
          #pragma unroll
          for (int s = 0; s < NWAVE; ++s) o += outred[s][tid];
          out[(size_t)tid * TT + t] = o;
        }
        __syncthreads();
      }
      ++bar;
      gbar(cnt, NWG * bar);
    }
  }
}

extern "C" void kernel_launch(void* const* d_in, const int* in_sizes, int n_in,
                              void* d_out, int out_size, void* d_ws, size_t ws_size,
                              hipStream_t stream) {
  (void)in_sizes; (void)n_in; (void)out_size;
  const float* x   = (const float*)d_in[0];
  const float* W1  = (const float*)d_in[1];
  const float* bW1 = (const float*)d_in[2];
  const float* U1  = (const float*)d_in[3];
  const float* bU1 = (const float*)d_in[4];
  const float* W2  = (const float*)d_in[5];
  const float* bW2 = (const float*)d_in[6];
  const float* U2  = (const float*)d_in[7];
  const float* bU2 = (const float*)d_in[8];
  const float* lw  = (const float*)d_in[9];
  const float* lb  = (const float*)d_in[10];

  float* out = (float*)d_out;
  float* ws  = (float*)d_ws;

  if (ws_size >= (size_t)WS_TOT_F * sizeof(float)) {
    prep_ws<<<(WS_TOT_F + 255) / 256, 256, 0, stream>>>(x, U1, W2, U2, ws);
    rnn_main<<<NWG, TPB, 0, stream>>>(W1, bW1, bU1, bW2, bU2, lw, lb, out,
                                      (int*)ws, ws + WS_H1_F, ws + WS_H2_F,
                                      ws + WS_BLOB_F, ws + WS_XT_F);
  } else {
    const int nzero = 16 + 4 * HID * B;
    zero_ws<<<(nzero + TPB - 1) / TPB, TPB, 0, stream>>>(ws, nzero);
    rnn_fallback<<<NWG, TPB, 0, stream>>>(x, W1, bW1, U1, bU1,
                                          W2, bW2, U2, bU2, lw, lb, out, ws);
  }
}

// Round 4
// 23398.723 us; speedup vs baseline: 1.9409x; 1.1961x over previous
//
#include <hip/hip_runtime.h>
#include <math.h>

#define HID 512
#define B 64
#define SEQT 1024
#define FUT 16
#define TT (SEQT + FUT)
#define NWG 256
#define TPB 512
#define NWAVE 8          // TPB/64
#define JPW 2            // hidden units owned per WG = HID/NWG
#define HB (HID * B)     // one h buffer, floats
#define BLOBF 12288      // floats per WG: 4096 (phase1) + 8192 (phase2)

// ws float layout (main path):
//   [0..511]               barrier block (ints):
//                            grp[g]  at int g*32      (g<8)
//                            root    at int 16
//                            go[g]   at int 256+g*32  (separate cachelines)
//   [512 .. +2HB)          h1 double buffer  (float4 tiles: h4[k>>2][b][k&3])
//   [.. +2HB)              h2 double buffer  (same layout)
//   [.. +NWG*BLOBF)        rearranged weight blobs (per WG)
//   [.. +SEQT*B)           xT (x transposed to [t][b])
#define WS_H1_F   512
#define WS_H2_F   (WS_H1_F + 2 * HB)
#define WS_BLOB_F (WS_H2_F + 2 * HB)
#define WS_XT_F   (WS_BLOB_F + NWG * BLOBF)
#define WS_TOT_F  (WS_XT_F + SEQT * B)

// -------- hierarchical grid barrier, RELAXED spin + single acquire fence -----
// Key: polling with ACQUIRE loads emits a cache invalidate per poll, which
// keeps every XCD L2 permanently invalidated (the round-2/3 stall). Spin
// RELAXED (coherent read from LIC, no inv), then ONE acquire fence at exit.
__device__ inline void gbar2(int* bb, int wg, int bar) {
  __syncthreads();
  if (threadIdx.x == 0) {
    __threadfence();  // release: publish this WG's h writes (L2 wb), once
    const int g = wg & 7;
    int old = __hip_atomic_fetch_add(bb + g * 32, 1, __ATOMIC_RELAXED,
                                     __HIP_MEMORY_SCOPE_AGENT);
    if (old == 32 * bar - 1) {          // last arrival in group
      int r = __hip_atomic_fetch_add(bb + 16, 1, __ATOMIC_RELAXED,
                                     __HIP_MEMORY_SCOPE_AGENT);
      if (r == 8 * bar - 1) {           // last group -> release all go flags
        #pragma unroll
        for (int g2 = 0; g2 < 8; ++g2)
          __hip_atomic_store(bb + 256 + g2 * 32, bar, __ATOMIC_RELAXED,
                             __HIP_MEMORY_SCOPE_AGENT);
      }
    }
    while (__hip_atomic_load(bb + 256 + g * 32, __ATOMIC_RELAXED,
                             __HIP_MEMORY_SCOPE_AGENT) < bar) {
      __builtin_amdgcn_s_sleep(8);      // ~512 cy between polls
    }
    __builtin_amdgcn_fence(__ATOMIC_ACQUIRE, "agent");  // ONE inv at exit
  }
  __syncthreads();
}

// ---------------- prep: zero state, rearrange weights, transpose x -----------
__global__ void __launch_bounds__(256) prep_ws(
    const float* __restrict__ x,
    const float* __restrict__ U1, const float* __restrict__ W2,
    const float* __restrict__ U2, float* __restrict__ ws)
{
  const int idx = blockIdx.x * blockDim.x + threadIdx.x;
  if (idx < WS_BLOB_F) {                       // barrier block + h buffers
    ws[idx] = 0.0f;
  }
  {
    const int i2 = idx - WS_BLOB_F;
    if (i2 >= 0 && i2 < NWG * BLOBF) {
      const int wg  = i2 / BLOBF;
      const int off = i2 - wg * BLOBF;
      const int j0  = wg * JPW;
      float v;
      if (off < 4096) {                        // phase1: [k*8 + r] = U1[row(r)][k]
        const int k = off >> 3, r = off & 7;
        const int row = (r >> 1) * HID + j0 + (r & 1);
        v = U1[(size_t)row * HID + k];
      } else {                                 // phase2: [k*16 + rr]
        const int o2 = off - 4096;
        const int k = o2 >> 4, rr = o2 & 15;
        const int r = rr & 7;
        const int row = (r >> 1) * HID + j0 + (r & 1);
        v = (rr < 8) ? W2[(size_t)row * HID + k] : U2[(size_t)row * HID + k];
      }
      ws[WS_BLOB_F + i2] = v;
    }
  }
  {
    const int i3 = idx - WS_XT_F;
    if (i3 >= 0 && i3 < SEQT * B) {
      const int t = i3 >> 6, b = i3 & 63;
      ws[WS_XT_F + i3] = x[(size_t)b * SEQT + t];
    }
  }
}

// ---------------- persistent 2-layer LSTM: LDS weights, float4 h -------------
__global__ void __launch_bounds__(TPB, 1) rnn_main(
    const float* __restrict__ W1, const float* __restrict__ bW1,
    const float* __restrict__ bU1,
    const float* __restrict__ bW2, const float* __restrict__ bU2,
    const float* __restrict__ lw, const float* __restrict__ lb,
    float* __restrict__ out,
    int* __restrict__ bb,
    float* __restrict__ h1b, float* __restrict__ h2b,
    const float* __restrict__ wbl, const float* __restrict__ xT)
{
  __shared__ float wlds[BLOBF];        // 48 KB persistent weight blob
  __shared__ float red[NWAVE][8][B];   // per-wave partial dots, 16 KB
  __shared__ float outred[NWAVE][B];   // WG0 output-head reduction, 2 KB
  __shared__ float c1s[JPW][B], c2s[JPW][B];
  __shared__ float w1c[8], bs1[8], bs2[8];

  const int wg   = blockIdx.x;
  const int j0   = wg * JPW;
  const int tid  = threadIdx.x;
  const int lane = tid & 63;
  const int wvu  = __builtin_amdgcn_readfirstlane(tid >> 6);

  // ---- one-time: copy this WG's weight blob into LDS ----
  {
    const float4* gsrc = (const float4*)(wbl + (size_t)wg * BLOBF);
    float4* ldst = (float4*)wlds;
    #pragma unroll
    for (int i = 0; i < BLOBF / 4 / TPB; ++i)
      ldst[i * TPB + tid] = gsrc[i * TPB + tid];
  }
  if (tid < JPW * B) { c1s[tid >> 6][lane] = 0.f; c2s[tid >> 6][lane] = 0.f; }
  if (tid < 8) {
    const int g = tid >> 1, jl = tid & 1;
    const int row = g * HID + j0 + jl;
    w1c[tid] = W1[row];
    bs1[tid] = bW1[row] + bU1[row];
    bs2[tid] = bW2[row] + bU2[row];
  }
  __syncthreads();

  const float* wl1 = wlds + wvu * 512;          // phase1 weights, this wave
  const float* wl2 = wlds + 4096 + wvu * 1024;  // phase2 weights, this wave
  const float lbv = lb[0];

  int bar = 0;
  for (int t = 0; t < TT; ++t) {
    const float* h1old = h1b + ((t + 1) & 1) * HB;
    float*       h1new = h1b + (t & 1) * HB;
    const float* h2old = h2b + ((t + 1) & 1) * HB;
    float*       h2new = h2b + (t & 1) * HB;

    // prefetch x for cell-1 (teacher region)
    float xvpref = 0.f;
    if (tid < JPW * B && t < SEQT) xvpref = xT[(size_t)t * B + lane];

    // -------- phase 1: gates1 = U1 h1(t-1) ----------------------------------
    {
      const float4* hp = (const float4*)h1old + (size_t)(wvu * 16) * B + lane;
      float4 hq[16];
      #pragma unroll
      for (int i = 0; i < 16; ++i) hq[i] = hp[i * B];
      float a[8] = {0.f,0.f,0.f,0.f,0.f,0.f,0.f,0.f};
      #pragma unroll
      for (int c = 0; c < 16; ++c) {            // k-quad within this wave's 64-k
        const float hh[4] = {hq[c].x, hq[c].y, hq[c].z, hq[c].w};
        #pragma unroll
        for (int j = 0; j < 4; ++j) {
          const float4 wA = *(const float4*)(wl1 + c * 32 + j * 8);
          const float4 wB = *(const float4*)(wl1 + c * 32 + j * 8 + 4);
          const float h = hh[j];
          a[0] = fmaf(wA.x, h, a[0]); a[1] = fmaf(wA.y, h, a[1]);
          a[2] = fmaf(wA.z, h, a[2]); a[3] = fmaf(wA.w, h, a[3]);
          a[4] = fmaf(wB.x, h, a[4]); a[5] = fmaf(wB.y, h, a[5]);
          a[6] = fmaf(wB.z, h, a[6]); a[7] = fmaf(wB.w, h, a[7]);
        }
      }
      #pragma unroll
      for (int r = 0; r < 8; ++r) red[wvu][r][lane] = a[r];
    }
    __syncthreads();

    // cell-1 elementwise (2 j's x 64 b = 128 threads)
    if (tid < JPW * B) {
      const int jl = tid >> 6, b = tid & 63;
      const float xv = (t < SEQT) ? xvpref : out[(size_t)b * TT + (t - 1)];
      float gate[4];
      #pragma unroll
      for (int g = 0; g < 4; ++g) {
        const int r = g * 2 + jl;
        float s = bs1[r] + xv * w1c[r];
        #pragma unroll
        for (int w = 0; w < NWAVE; ++w) s += red[w][r][b];
        gate[g] = s;
      }
      const float c = gate[1] * c1s[jl][b] + gate[0] * gate[2];
      c1s[jl][b] = c;
      const int j = j0 + jl;
      h1new[(size_t)(j >> 2) * (B * 4) + b * 4 + (j & 3)] = gate[3] * tanhf(c);
    }

    ++bar;
    gbar2(bb, wg, bar);

    // WG0: output head for step t-1 (teacher region), overlapped with phase 2
    if (wg == 0 && t >= 1 && t <= SEQT - 1) {
      const float4* hb2 = (const float4*)h2old + (size_t)(wvu * 16) * B + lane;
      const float4* lw4 = (const float4*)lw + wvu * 16;
      float p = 0.f;
      #pragma unroll
      for (int i = 0; i < 16; ++i) {
        const float4 hv = hb2[i * B];
        const float4 wv = lw4[i];
        p = fmaf(wv.x, hv.x, p); p = fmaf(wv.y, hv.y, p);
        p = fmaf(wv.z, hv.z, p); p = fmaf(wv.w, hv.w, p);
      }
      outred[wvu][lane] = p;
      __syncthreads();
      if (tid < B) {
        float o = lbv;
        #pragma unroll
        for (int s = 0; s < NWAVE; ++s) o += outred[s][tid];
        out[(size_t)tid * TT + (t - 1)] = o;
      }
      __syncthreads();
    }

    // -------- phase 2: gates2 = W2 h1(t) + U2 h2(t-1) ------------------------
    {
      const float4* pp4 = (const float4*)h1new + (size_t)(wvu * 16) * B + lane;
      const float4* qq4 = (const float4*)h2old + (size_t)(wvu * 16) * B + lane;
      float4 P[16], Q[16];
      #pragma unroll
      for (int i = 0; i < 16; ++i) P[i] = pp4[i * B];
      #pragma unroll
      for (int i = 0; i < 16; ++i) Q[i] = qq4[i * B];
      float a[8] = {0.f,0.f,0.f,0.f,0.f,0.f,0.f,0.f};
      #pragma unroll
      for (int c = 0; c < 16; ++c) {
        const float hp_[4] = {P[c].x, P[c].y, P[c].z, P[c].w};
        const float hq_[4] = {Q[c].x, Q[c].y, Q[c].z, Q[c].w};
        #pragma unroll
        for (int j = 0; j < 4; ++j) {
          const float4 w0 = *(const float4*)(wl2 + c * 64 + j * 16);
          const float4 w1 = *(const float4*)(wl2 + c * 64 + j * 16 + 4);
          const float4 w2 = *(const float4*)(wl2 + c * 64 + j * 16 + 8);
          const float4 w3 = *(const float4*)(wl2 + c * 64 + j * 16 + 12);
          const float hp1 = hp_[j], hq1 = hq_[j];
          a[0] = fmaf(w0.x, hp1, a[0]); a[1] = fmaf(w0.y, hp1, a[1]);
          a[2] = fmaf(w0.z, hp1, a[2]); a[3] = fmaf(w0.w, hp1, a[3]);
          a[4] = fmaf(w1.x, hp1, a[4]); a[5] = fmaf(w1.y, hp1, a[5]);
          a[6] = fmaf(w1.z, hp1, a[6]); a[7] = fmaf(w1.w, hp1, a[7]);
          a[0] = fmaf(w2.x, hq1, a[0]); a[1] = fmaf(w2.y, hq1, a[1]);
          a[2] = fmaf(w2.z, hq1, a[2]); a[3] = fmaf(w2.w, hq1, a[3]);
          a[4] = fmaf(w3.x, hq1, a[4]); a[5] = fmaf(w3.y, hq1, a[5]);
          a[6] = fmaf(w3.z, hq1, a[6]); a[7] = fmaf(w3.w, hq1, a[7]);
        }
      }
      #pragma unroll
      for (int r = 0; r < 8; ++r) red[wvu][r][lane] = a[r];
    }
    __syncthreads();

    // cell-2 elementwise
    if (tid < JPW * B) {
      const int jl = tid >> 6, b = tid & 63;
      float gate[4];
      #pragma unroll
      for (int g = 0; g < 4; ++g) {
        const int r = g * 2 + jl;
        float s = bs2[r];
        #pragma unroll
        for (int w = 0; w < NWAVE; ++w) s += red[w][r][b];
        gate[g] = s;
      }
      const float c = gate[1] * c2s[jl][b] + gate[0] * gate[2];
      c2s[jl][b] = c;
      const int j = j0 + jl;
      h2new[(size_t)(j >> 2) * (B * 4) + b * 4 + (j & 3)] = gate[3] * tanhf(c);
    }
    __syncthreads();  // protect red[] before next step's phase-1 writes

    // Autoregressive region: out(t) must be globally visible before phase1(t+1)
    if (t >= SEQT - 1) {
      ++bar;
      gbar2(bb, wg, bar);
      if (wg == 0) {
        const float4* hb2 = (const float4*)h2new + (size_t)(wvu * 16) * B + lane;
        const float4* lw4 = (const float4*)lw + wvu * 16;
        float p = 0.f;
        #pragma unroll
        for (int i = 0; i < 16; ++i) {
          const float4 hv = hb2[i * B];
          const float4 wv = lw4[i];
          p = fmaf(wv.x, hv.x, p); p = fmaf(wv.y, hv.y, p);
          p = fmaf(wv.z, hv.z, p); p = fmaf(wv.w, hv.w, p);
        }
        outred[wvu][lane] = p;
        __syncthreads();
        if (tid < B) {
          float o = lbv;
          #pragma unroll
          for (int s = 0; s < NWAVE; ++s) o += outred[s][tid];
          out[(size_t)tid * TT + t] = o;
        }
        __syncthreads();
      }
      ++bar;
      gbar2(bb, wg, bar);
    }
  }
}

// =================== fallback path (round-0 kernel, known correct) ===========
__device__ inline void gbar(int* cnt, int target) {
  __syncthreads();
  if (threadIdx.x == 0) {
    __threadfence();
    __hip_atomic_fetch_add(cnt, 1, __ATOMIC_RELEASE, __HIP_MEMORY_SCOPE_AGENT);
    while (__hip_atomic_load(cnt, __ATOMIC_ACQUIRE, __HIP_MEMORY_SCOPE_AGENT) < target) {
      __builtin_amdgcn_s_sleep(2);
    }
  }
  __syncthreads();
}

__global__ void __launch_bounds__(TPB) zero_ws(float* ws, int n) {
  int i = blockIdx.x * blockDim.x + threadIdx.x;
  if (i < n) ws[i] = 0.0f;
}

__global__ void __launch_bounds__(TPB) rnn_fallback(
    const float* __restrict__ x,
    const float* __restrict__ W1, const float* __restrict__ bW1,
    const float* __restrict__ U1, const float* __restrict__ bU1,
    const float* __restrict__ W2, const float* __restrict__ bW2,
    const float* __restrict__ U2, const float* __restrict__ bU2,
    const float* __restrict__ lw, const float* __restrict__ lb,
    float* out, float* ws)
{
  __shared__ float red[NWAVE][8][B];
  __shared__ float outred[NWAVE][B];
  __shared__ float c1s[JPW][B], c2s[JPW][B];
  __shared__ float w1c[8], bs1[8], bs2[8];

  int* cnt   = (int*)ws;
  float* h1b = ws + 16;
  float* h2b = h1b + 2 * HB;

  const int wg   = blockIdx.x;
  const int j0   = wg * JPW;
  const int tid  = threadIdx.x;
  const int lane = tid & 63;
  const int wvu  = __builtin_amdgcn_readfirstlane(tid >> 6);
  const int kb   = wvu << 6;

  if (tid < JPW * B) { c1s[tid >> 6][lane] = 0.f; c2s[tid >> 6][lane] = 0.f; }
  if (tid < 8) {
    const int g = tid >> 1, jl = tid & 1;
    const int row = g * HID + j0 + jl;
    w1c[tid] = W1[row];
    bs1[tid] = bW1[row] + bU1[row];
    bs2[tid] = bW2[row] + bU2[row];
  }
  __syncthreads();

  const float* u1p[8]; const float* w2p[8]; const float* u2p[8];
  #pragma unroll
  for (int r = 0; r < 8; ++r) {
    const int row = (r >> 1) * HID + j0 + (r & 1);
    u1p[r] = U1 + (size_t)row * HID + kb;
    w2p[r] = W2 + (size_t)row * HID + kb;
    u2p[r] = U2 + (size_t)row * HID + kb;
  }
  const float lbv = lb[0];

  int bar = 0;
  for (int t = 0; t < TT; ++t) {
    const float* h1old = h1b + ((t + 1) & 1) * HB;
    float*       h1new = h1b + (t & 1) * HB;
    const float* h2old = h2b + ((t + 1) & 1) * HB;
    float*       h2new = h2b + (t & 1) * HB;

    {
      const float* hp = h1old + (size_t)kb * B;
      float a0=0.f,a1=0.f,a2=0.f,a3=0.f,a4=0.f,a5=0.f,a6=0.f,a7=0.f;
      #pragma unroll 8
      for (int k = 0; k < 64; ++k) {
        const float hv = hp[k * B + lane];
        a0 = fmaf(u1p[0][k], hv, a0); a1 = fmaf(u1p[1][k], hv, a1);
        a2 = fmaf(u1p[2][k], hv, a2); a3 = fmaf(u1p[3][k], hv, a3);
        a4 = fmaf(u1p[4][k], hv, a4); a5 = fmaf(u1p[5][k], hv, a5);
        a6 = fmaf(u1p[6][k], hv, a6); a7 = fmaf(u1p[7][k], hv, a7);
      }
      red[wvu][0][lane]=a0; red[wvu][1][lane]=a1; red[wvu][2][lane]=a2; red[wvu][3][lane]=a3;
      red[wvu][4][lane]=a4; red[wvu][5][lane]=a5; red[wvu][6][lane]=a6; red[wvu][7][lane]=a7;
    }
    __syncthreads();

    if (tid < JPW * B) {
      const int jl = tid >> 6, b = tid & 63;
      const float xv = (t < SEQT) ? x[(size_t)b * SEQT + t]
                                  : out[(size_t)b * TT + (t - 1)];
      float gate[4];
      #pragma unroll
      for (int g = 0; g < 4; ++g) {
        const int r = g * 2 + jl;
        float s = bs1[r] + xv * w1c[r];
        #pragma unroll
        for (int w = 0; w < NWAVE; ++w) s += red[w][r][b];
        gate[g] = s;
      }
      const float c = gate[1] * c1s[jl][b] + gate[0] * gate[2];
      c1s[jl][b] = c;
      h1new[(size_t)(j0 + jl) * B + b] = gate[3] * tanhf(c);
    }

    ++bar;
    gbar(cnt, NWG * bar);

    if (wg == 0 && t >= 1 && t <= SEQT - 1) {
      const float* hb2 = h2old + (size_t)(wvu * 64) * B;
      const float* lwp = lw + wvu * 64;
      float p = 0.f;
      #pragma unroll 8
      for (int j = 0; j < 64; ++j) p = fmaf(lwp[j], hb2[j * B + lane], p);
      outred[wvu][lane] = p;
      __syncthreads();
      if (tid < B) {
        float o = lbv;
        #pragma unroll
        for (int s = 0; s < NWAVE; ++s) o += outred[s][tid];
        out[(size_t)tid * TT + (t - 1)] = o;
      }
      __syncthreads();
    }

    {
      const float* h1p = h1new + (size_t)kb * B;
      const float* h2p = h2old + (size_t)kb * B;
      float s0=0.f,s1=0.f,s2=0.f,s3=0.f,s4=0.f,s5=0.f,s6=0.f,s7=0.f;
      float q0=0.f,q1=0.f,q2=0.f,q3=0.f,q4=0.f,q5=0.f,q6=0.f,q7=0.f;
      #pragma unroll 4
      for (int k = 0; k < 64; ++k) {
        const float h1v = h1p[k * B + lane];
        const float h2v = h2p[k * B + lane];
        s0 = fmaf(w2p[0][k], h1v, s0); q0 = fmaf(u2p[0][k], h2v, q0);
        s1 = fmaf(w2p[1][k], h1v, s1); q1 = fmaf(u2p[1][k], h2v, q1);
        s2 = fmaf(w2p[2][k], h1v, s2); q2 = fmaf(u2p[2][k], h2v, q2);
        s3 = fmaf(w2p[3][k], h1v, s3); q3 = fmaf(u2p[3][k], h2v, q3);
        s4 = fmaf(w2p[4][k], h1v, s4); q4 = fmaf(u2p[4][k], h2v, q4);
        s5 = fmaf(w2p[5][k], h1v, s5); q5 = fmaf(u2p[5][k], h2v, q5);
        s6 = fmaf(w2p[6][k], h1v, s6); q6 = fmaf(u2p[6][k], h2v, q6);
        s7 = fmaf(w2p[7][k], h1v, s7); q7 = fmaf(u2p[7][k], h2v, q7);
      }
      red[wvu][0][lane]=s0+q0; red[wvu][1][lane]=s1+q1;
      red[wvu][2][lane]=s2+q2; red[wvu][3][lane]=s3+q3;
      red[wvu][4][lane]=s4+q4; red[wvu][5][lane]=s5+q5;
      red[wvu][6][lane]=s6+q6; red[wvu][7][lane]=s7+q7;
    }
    __syncthreads();

    if (tid < JPW * B) {
      const int jl = tid >> 6, b = tid & 63;
      float gate[4];
      #pragma unroll
      for (int g = 0; g < 4; ++g) {
        const int r = g * 2 + jl;
        float s = bs2[r];
        #pragma unroll
        for (int w = 0; w < NWAVE; ++w) s += red[w][r][b];
        gate[g] = s;
      }
      const float c = gate[1] * c2s[jl][b] + gate[0] * gate[2];
      c2s[jl][b] = c;
      h2new[(size_t)(j0 + jl) * B + b] = gate[3] * tanhf(c);
    }
    __syncthreads();

    if (t >= SEQT - 1) {
      ++bar;
      gbar(cnt, NWG * bar);
      if (wg == 0) {
        const float* hb2 = h2new + (size_t)(wvu * 64) * B;
        const float* lwp = lw + wvu * 64;
        float p = 0.f;
        #pragma unroll 8
        for (int j = 0; j < 64; ++j) p = fmaf(lwp[j], hb2[j * B + lane], p);
        outred[wvu][lane] = p;
        __syncthreads();
        if (tid < B) {
          float o = lbv;
          #pragma unroll
          for (int s = 0; s < NWAVE; ++s) o += outred[s][tid];
          out[(size_t)tid * TT + t] = o;
        }
        __syncthreads();
      }
      ++bar;
      gbar(cnt, NWG * bar);
    }
  }
}

extern "C" void kernel_launch(void* const* d_in, const int* in_sizes, int n_in,
                              void* d_out, int out_size, void* d_ws, size_t ws_size,
                              hipStream_t stream) {
  (void)in_sizes; (void)n_in; (void)out_size;
  const float* x   = (const float*)d_in[0];
  const float* W1  = (const float*)d_in[1];
  const float* bW1 = (const float*)d_in[2];
  const float* U1  = (const float*)d_in[3];
  const float* bU1 = (const float*)d_in[4];
  const float* W2  = (const float*)d_in[5];
  const float* bW2 = (const float*)d_in[6];
  const float* U2  = (const float*)d_in[7];
  const float* bU2 = (const float*)d_in[8];
  const float* lw  = (const float*)d_in[9];
  const float* lb  = (const float*)d_in[10];

  float* out = (float*)d_out;
  float* ws  = (float*)d_ws;

  if (ws_size >= (size_t)WS_TOT_F * sizeof(float)) {
    prep_ws<<<(WS_TOT_F + 255) / 256, 256, 0, stream>>>(x, U1, W2, U2, ws);
    rnn_main<<<NWG, TPB, 0, stream>>>(W1, bW1, bU1, bW2, bU2, lw, lb, out,
                                      (int*)ws, ws + WS_H1_F, ws + WS_H2_F,
                                      ws + WS_BLOB_F, ws + WS_XT_F);
  } else {
    const int nzero = 16 + 4 * HID * B;
    zero_ws<<<(nzero + TPB - 1) / TPB, TPB, 0, stream>>>(ws, nzero);
    rnn_fallback<<<NWG, TPB, 0, stream>>>(x, W1, bW1, U1, bU1,
                                          W2, bW2, U2, bU2, lw, lb, out, ws);
  }
}

// Round 5
// 22748.486 us; speedup vs baseline: 1.9964x; 1.0286x over previous
//
#include <hip/hip_runtime.h>
#include <math.h>

#define HID 512
#define B 64
#define SEQT 1024
#define FUT 16
#define TT (SEQT + FUT)
#define NWG 256
#define TPB 512
#define NWAVE 8          // TPB/64
#define JPW 2            // hidden units owned per WG = HID/NWG
#define HB (HID * B)     // one h buffer, floats
#define BLOBF 12288      // floats per WG: 4096 (phase1) + 8192 (phase2)

// ws float layout (main path):
//   [0..511]               barrier block (ints):
//                            slot[wg] at int wg   (wg<256)
//                            go       at int 320  (own cacheline)
//   [512 .. +2HB)          h1 double buffer  (float4 tiles: h4[k>>2][b][k&3])
//   [.. +2HB)              h2 double buffer  (same layout)
//   [.. +NWG*BLOBF)        rearranged weight blobs (per WG)
//   [.. +SEQT*B)           xT (x transposed to [t][b])
#define WS_H1_F   512
#define WS_H2_F   (WS_H1_F + 2 * HB)
#define WS_BLOB_F (WS_H2_F + 2 * HB)
#define WS_XT_F   (WS_BLOB_F + NWG * BLOBF)
#define WS_TOT_F  (WS_XT_F + SEQT * B)

// ---- grid barrier v3: slot-store arrivals + leader vector poll + 1 go flag --
// Design rules learned in r2-r4:
//  * no RMW atomics on arrival (32 RMWs/line serialize at LIC ~2.4us)
//  * spin with RELAXED loads (ACQUIRE-per-poll = buffer_inv per poll = L2 dead)
//  * the ONE acquire fence (buffer_inv) goes BEFORE the spin, not after: at
//    `go` time every XCD L2 is clean and nobody invalidates after go, so the
//    32 WGs of an XCD share one LIC fetch of h instead of 32 (96->~3 MB/step).
__device__ inline void gbar3(int* bb, int wg, int bar) {
  __syncthreads();
  const int tid  = threadIdx.x;
  const int lane = tid & 63;
  if (tid == 0) {
    __threadfence();  // release: push this WG's h writes to LIC (wbl2+waitcnt)
    __hip_atomic_store(bb + wg, bar, __ATOMIC_RELAXED, __HIP_MEMORY_SCOPE_AGENT);
    // pre-spin invalidate: drop stale h lines NOW, while we wait anyway
    __builtin_amdgcn_fence(__ATOMIC_ACQUIRE, "agent");
  }
  if (wg == NWG - 1 && tid < 64) {
    // leader wave: poll all 256 arrival slots (4 uncached dwords per lane)
    for (;;) {
      int a = __hip_atomic_load(bb + lane,       __ATOMIC_RELAXED, __HIP_MEMORY_SCOPE_AGENT);
      int b = __hip_atomic_load(bb + 64  + lane, __ATOMIC_RELAXED, __HIP_MEMORY_SCOPE_AGENT);
      int c = __hip_atomic_load(bb + 128 + lane, __ATOMIC_RELAXED, __HIP_MEMORY_SCOPE_AGENT);
      int d = __hip_atomic_load(bb + 192 + lane, __ATOMIC_RELAXED, __HIP_MEMORY_SCOPE_AGENT);
      if (__all(a >= bar && b >= bar && c >= bar && d >= bar)) break;
      __builtin_amdgcn_s_sleep(2);
    }
    __builtin_amdgcn_fence(__ATOMIC_ACQUIRE, "workgroup");  // order loads->store
    if (lane == 0)
      __hip_atomic_store(bb + 320, bar, __ATOMIC_RELAXED, __HIP_MEMORY_SCOPE_AGENT);
  }
  if (tid == 0) {
    while (__hip_atomic_load(bb + 320, __ATOMIC_RELAXED,
                             __HIP_MEMORY_SCOPE_AGENT) < bar) {
      __builtin_amdgcn_s_sleep(2);
    }
  }
  __syncthreads();  // compiler+wave barrier; h loads below stay below
}

// ---------------- prep: zero state, rearrange weights, transpose x -----------
__global__ void __launch_bounds__(256) prep_ws(
    const float* __restrict__ x,
    const float* __restrict__ U1, const float* __restrict__ W2,
    const float* __restrict__ U2, float* __restrict__ ws)
{
  const int idx = blockIdx.x * blockDim.x + threadIdx.x;
  if (idx < WS_BLOB_F) {                       // barrier block + h buffers
    ws[idx] = 0.0f;
  }
  {
    const int i2 = idx - WS_BLOB_F;
    if (i2 >= 0 && i2 < NWG * BLOBF) {
      const int wg  = i2 / BLOBF;
      const int off = i2 - wg * BLOBF;
      const int j0  = wg * JPW;
      float v;
      if (off < 4096) {                        // phase1: [k*8 + r] = U1[row(r)][k]
        const int k = off >> 3, r = off & 7;
        const int row = (r >> 1) * HID + j0 + (r & 1);
        v = U1[(size_t)row * HID + k];
      } else {                                 // phase2: [k*16 + rr]
        const int o2 = off - 4096;
        const int k = o2 >> 4, rr = o2 & 15;
        const int r = rr & 7;
        const int row = (r >> 1) * HID + j0 + (r & 1);
        v = (rr < 8) ? W2[(size_t)row * HID + k] : U2[(size_t)row * HID + k];
      }
      ws[WS_BLOB_F + i2] = v;
    }
  }
  {
    const int i3 = idx - WS_XT_F;
    if (i3 >= 0 && i3 < SEQT * B) {
      const int t = i3 >> 6, b = i3 & 63;
      ws[WS_XT_F + i3] = x[(size_t)b * SEQT + t];
    }
  }
}

// ---------------- persistent 2-layer LSTM: LDS weights, float4 h -------------
__global__ void __launch_bounds__(TPB, 1) rnn_main(
    const float* __restrict__ W1, const float* __restrict__ bW1,
    const float* __restrict__ bU1,
    const float* __restrict__ bW2, const float* __restrict__ bU2,
    const float* __restrict__ lw, const float* __restrict__ lb,
    float* __restrict__ out,
    int* __restrict__ bb,
    float* __restrict__ h1b, float* __restrict__ h2b,
    const float* __restrict__ wbl, const float* __restrict__ xT)
{
  __shared__ float wlds[BLOBF];        // 48 KB persistent weight blob
  __shared__ float red[NWAVE][8][B];   // per-wave partial dots, 16 KB
  __shared__ float outred[NWAVE][B];   // output-head reduction, 2 KB
  __shared__ float c1s[JPW][B], c2s[JPW][B];
  __shared__ float w1c[8], bs1[8], bs2[8];

  const int wg   = blockIdx.x;
  const int j0   = wg * JPW;
  const int tid  = threadIdx.x;
  const int lane = tid & 63;
  const int wvu  = __builtin_amdgcn_readfirstlane(tid >> 6);

  // ---- one-time: copy this WG's weight blob into LDS ----
  {
    const float4* gsrc = (const float4*)(wbl + (size_t)wg * BLOBF);
    float4* ldst = (float4*)wlds;
    #pragma unroll
    for (int i = 0; i < BLOBF / 4 / TPB; ++i)
      ldst[i * TPB + tid] = gsrc[i * TPB + tid];
  }
  if (tid < JPW * B) { c1s[tid >> 6][lane] = 0.f; c2s[tid >> 6][lane] = 0.f; }
  if (tid < 8) {
    const int g = tid >> 1, jl = tid & 1;
    const int row = g * HID + j0 + jl;
    w1c[tid] = W1[row];
    bs1[tid] = bW1[row] + bU1[row];
    bs2[tid] = bW2[row] + bU2[row];
  }
  __syncthreads();

  const float* wl1 = wlds + wvu * 512;          // phase1 weights, this wave
  const float* wl2 = wlds + 4096 + wvu * 1024;  // phase2 weights, this wave
  const float lbv = lb[0];

  int bar = 0;
  for (int t = 0; t < TT; ++t) {
    const float* h1old = h1b + ((t + 1) & 1) * HB;
    float*       h1new = h1b + (t & 1) * HB;
    const float* h2old = h2b + ((t + 1) & 1) * HB;
    float*       h2new = h2b + (t & 1) * HB;

    // prefetch x for cell-1 (teacher region)
    float xvpref = 0.f;
    if (tid < JPW * B && t < SEQT) xvpref = xT[(size_t)t * B + lane];

    // -------- phase 1: gates1 = U1 h1(t-1) ----------------------------------
    {
      const float4* hp = (const float4*)h1old + (size_t)(wvu * 16) * B + lane;
      float4 hq[16];
      #pragma unroll
      for (int i = 0; i < 16; ++i) hq[i] = hp[i * B];
      float a[8] = {0.f,0.f,0.f,0.f,0.f,0.f,0.f,0.f};
      #pragma unroll
      for (int c = 0; c < 16; ++c) {            // k-quad within this wave's 64-k
        const float hh[4] = {hq[c].x, hq[c].y, hq[c].z, hq[c].w};
        #pragma unroll
        for (int j = 0; j < 4; ++j) {
          const float4 wA = *(const float4*)(wl1 + c * 32 + j * 8);
          const float4 wB = *(const float4*)(wl1 + c * 32 + j * 8 + 4);
          const float h = hh[j];
          a[0] = fmaf(wA.x, h, a[0]); a[1] = fmaf(wA.y, h, a[1]);
          a[2] = fmaf(wA.z, h, a[2]); a[3] = fmaf(wA.w, h, a[3]);
          a[4] = fmaf(wB.x, h, a[4]); a[5] = fmaf(wB.y, h, a[5]);
          a[6] = fmaf(wB.z, h, a[6]); a[7] = fmaf(wB.w, h, a[7]);
        }
      }
      #pragma unroll
      for (int r = 0; r < 8; ++r) red[wvu][r][lane] = a[r];
    }
    __syncthreads();

    // cell-1 elementwise (2 j's x 64 b = 128 threads)
    if (tid < JPW * B) {
      const int jl = tid >> 6, b = tid & 63;
      const float xv = (t < SEQT) ? xvpref : out[(size_t)b * TT + (t - 1)];
      float gate[4];
      #pragma unroll
      for (int g = 0; g < 4; ++g) {
        const int r = g * 2 + jl;
        float s = bs1[r] + xv * w1c[r];
        #pragma unroll
        for (int w = 0; w < NWAVE; ++w) s += red[w][r][b];
        gate[g] = s;
      }
      const float c = gate[1] * c1s[jl][b] + gate[0] * gate[2];
      c1s[jl][b] = c;
      const int j = j0 + jl;
      h1new[(size_t)(j >> 2) * (B * 4) + b * 4 + (j & 3)] = gate[3] * tanhf(c);
    }

    ++bar;
    gbar3(bb, wg, bar);

    // duty WG (round-robin, never the leader WG 255): output head for t-1,
    // overlapped with the other WGs' phase 2. h2(t-1) published by barrier.
    if (wg == (t & 127) && t >= 1 && t <= SEQT - 1) {
      const float4* hb2 = (const float4*)h2old + (size_t)(wvu * 16) * B + lane;
      const float4* lw4 = (const float4*)lw + wvu * 16;
      float p = 0.f;
      #pragma unroll
      for (int i = 0; i < 16; ++i) {
        const float4 hv = hb2[i * B];
        const float4 wv = lw4[i];
        p = fmaf(wv.x, hv.x, p); p = fmaf(wv.y, hv.y, p);
        p = fmaf(wv.z, hv.z, p); p = fmaf(wv.w, hv.w, p);
      }
      outred[wvu][lane] = p;
      __syncthreads();
      if (tid < B) {
        float o = lbv;
        #pragma unroll
        for (int s = 0; s < NWAVE; ++s) o += outred[s][tid];
        out[(size_t)tid * TT + (t - 1)] = o;
      }
      __syncthreads();
    }

    // -------- phase 2: gates2 = W2 h1(t) + U2 h2(t-1) ------------------------
    {
      const float4* pp4 = (const float4*)h1new + (size_t)(wvu * 16) * B + lane;
      const float4* qq4 = (const float4*)h2old + (size_t)(wvu * 16) * B + lane;
      float4 P[16], Q[16];
      #pragma unroll
      for (int i = 0; i < 16; ++i) P[i] = pp4[i * B];
      #pragma unroll
      for (int i = 0; i < 16; ++i) Q[i] = qq4[i * B];
      float a[8] = {0.f,0.f,0.f,0.f,0.f,0.f,0.f,0.f};
      #pragma unroll
      for (int c = 0; c < 16; ++c) {
        const float hp_[4] = {P[c].x, P[c].y, P[c].z, P[c].w};
        const float hq_[4] = {Q[c].x, Q[c].y, Q[c].z, Q[c].w};
        #pragma unroll
        for (int j = 0; j < 4; ++j) {
          const float4 w0 = *(const float4*)(wl2 + c * 64 + j * 16);
          const float4 w1 = *(const float4*)(wl2 + c * 64 + j * 16 + 4);
          const float4 w2 = *(const float4*)(wl2 + c * 64 + j * 16 + 8);
          const float4 w3 = *(const float4*)(wl2 + c * 64 + j * 16 + 12);
          const float hp1 = hp_[j], hq1 = hq_[j];
          a[0] = fmaf(w0.x, hp1, a[0]); a[1] = fmaf(w0.y, hp1, a[1]);
          a[2] = fmaf(w0.z, hp1, a[2]); a[3] = fmaf(w0.w, hp1, a[3]);
          a[4] = fmaf(w1.x, hp1, a[4]); a[5] = fmaf(w1.y, hp1, a[5]);
          a[6] = fmaf(w1.z, hp1, a[6]); a[7] = fmaf(w1.w, hp1, a[7]);
          a[0] = fmaf(w2.x, hq1, a[0]); a[1] = fmaf(w2.y, hq1, a[1]);
          a[2] = fmaf(w2.z, hq1, a[2]); a[3] = fmaf(w2.w, hq1, a[3]);
          a[4] = fmaf(w3.x, hq1, a[4]); a[5] = fmaf(w3.y, hq1, a[5]);
          a[6] = fmaf(w3.z, hq1, a[6]); a[7] = fmaf(w3.w, hq1, a[7]);
        }
      }
      #pragma unroll
      for (int r = 0; r < 8; ++r) red[wvu][r][lane] = a[r];
    }
    __syncthreads();

    // cell-2 elementwise
    if (tid < JPW * B) {
      const int jl = tid >> 6, b = tid & 63;
      float gate[4];
      #pragma unroll
      for (int g = 0; g < 4; ++g) {
        const int r = g * 2 + jl;
        float s = bs2[r];
        #pragma unroll
        for (int w = 0; w < NWAVE; ++w) s += red[w][r][b];
        gate[g] = s;
      }
      const float c = gate[1] * c2s[jl][b] + gate[0] * gate[2];
      c2s[jl][b] = c;
      const int j = j0 + jl;
      h2new[(size_t)(j >> 2) * (B * 4) + b * 4 + (j & 3)] = gate[3] * tanhf(c);
    }
    __syncthreads();  // protect red[] before next step's phase-1 writes

    // Autoregressive region: out(t) must be globally visible before phase1(t+1)
    if (t >= SEQT - 1) {
      ++bar;
      gbar3(bb, wg, bar);
      if (wg == 0) {
        const float4* hb2 = (const float4*)h2new + (size_t)(wvu * 16) * B + lane;
        const float4* lw4 = (const float4*)lw + wvu * 16;
        float p = 0.f;
        #pragma unroll
        for (int i = 0; i < 16; ++i) {
          const float4 hv = hb2[i * B];
          const float4 wv = lw4[i];
          p = fmaf(wv.x, hv.x, p); p = fmaf(wv.y, hv.y, p);
          p = fmaf(wv.z, hv.z, p); p = fmaf(wv.w, hv.w, p);
        }
        outred[wvu][lane] = p;
        __syncthreads();
        if (tid < B) {
          float o = lbv;
          #pragma unroll
          for (int s = 0; s < NWAVE; ++s) o += outred[s][tid];
          out[(size_t)tid * TT + t] = o;
        }
        __syncthreads();
      }
      ++bar;
      gbar3(bb, wg, bar);
    }
  }
}

// =================== fallback path (round-0 kernel, known correct) ===========
__device__ inline void gbar(int* cnt, int target) {
  __syncthreads();
  if (threadIdx.x == 0) {
    __threadfence();
    __hip_atomic_fetch_add(cnt, 1, __ATOMIC_RELEASE, __HIP_MEMORY_SCOPE_AGENT);
    while (__hip_atomic_load(cnt, __ATOMIC_ACQUIRE, __HIP_MEMORY_SCOPE_AGENT) < target) {
      __builtin_amdgcn_s_sleep(2);
    }
  }
  __syncthreads();
}

__global__ void __launch_bounds__(TPB) zero_ws(float* ws, int n) {
  int i = blockIdx.x * blockDim.x + threadIdx.x;
  if (i < n) ws[i] = 0.0f;
}

__global__ void __launch_bounds__(TPB) rnn_fallback(
    const float* __restrict__ x,
    const float* __restrict__ W1, const float* __restrict__ bW1,
    const float* __restrict__ U1, const float* __restrict__ bU1,
    const float* __restrict__ W2, const float* __restrict__ bW2,
    const float* __restrict__ U2, const float* __restrict__ bU2,
    const float* __restrict__ lw, const float* __restrict__ lb,
    float* out, float* ws)
{
  __shared__ float red[NWAVE][8][B];
  __shared__ float outred[NWAVE][B];
  __shared__ float c1s[JPW][B], c2s[JPW][B];
  __shared__ float w1c[8], bs1[8], bs2[8];

  int* cnt   = (int*)ws;
  float* h1b = ws + 16;
  float* h2b = h1b + 2 * HB;

  const int wg   = blockIdx.x;
  const int j0   = wg * JPW;
  const int tid  = threadIdx.x;
  const int lane = tid & 63;
  const int wvu  = __builtin_amdgcn_readfirstlane(tid >> 6);
  const int kb   = wvu << 6;

  if (tid < JPW * B) { c1s[tid >> 6][lane] = 0.f; c2s[tid >> 6][lane] = 0.f; }
  if (tid < 8) {
    const int g = tid >> 1, jl = tid & 1;
    const int row = g * HID + j0 + jl;
    w1c[tid] = W1[row];
    bs1[tid] = bW1[row] + bU1[row];
    bs2[tid] = bW2[row] + bU2[row];
  }
  __syncthreads();

  const float* u1p[8]; const float* w2p[8]; const float* u2p[8];
  #pragma unroll
  for (int r = 0; r < 8; ++r) {
    const int row = (r >> 1) * HID + j0 + (r & 1);
    u1p[r] = U1 + (size_t)row * HID + kb;
    w2p[r] = W2 + (size_t)row * HID + kb;
    u2p[r] = U2 + (size_t)row * HID + kb;
  }
  const float lbv = lb[0];

  int bar = 0;
  for (int t = 0; t < TT; ++t) {
    const float* h1old = h1b + ((t + 1) & 1) * HB;
    float*       h1new = h1b + (t & 1) * HB;
    const float* h2old = h2b + ((t + 1) & 1) * HB;
    float*       h2new = h2b + (t & 1) * HB;

    {
      const float* hp = h1old + (size_t)kb * B;
      float a0=0.f,a1=0.f,a2=0.f,a3=0.f,a4=0.f,a5=0.f,a6=0.f,a7=0.f;
      #pragma unroll 8
      for (int k = 0; k < 64; ++k) {
        const float hv = hp[k * B + lane];
        a0 = fmaf(u1p[0][k], hv, a0); a1 = fmaf(u1p[1][k], hv, a1);
        a2 = fmaf(u1p[2][k], hv, a2); a3 = fmaf(u1p[3][k], hv, a3);
        a4 = fmaf(u1p[4][k], hv, a4); a5 = fmaf(u1p[5][k], hv, a5);
        a6 = fmaf(u1p[6][k], hv, a6); a7 = fmaf(u1p[7][k], hv, a7);
      }
      red[wvu][0][lane]=a0; red[wvu][1][lane]=a1; red[wvu][2][lane]=a2; red[wvu][3][lane]=a3;
      red[wvu][4][lane]=a4; red[wvu][5][lane]=a5; red[wvu][6][lane]=a6; red[wvu][7][lane]=a7;
    }
    __syncthreads();

    if (tid < JPW * B) {
      const int jl = tid >> 6, b = tid & 63;
      const float xv = (t < SEQT) ? x[(size_t)b * SEQT + t]
                                  : out[(size_t)b * TT + (t - 1)];
      float gate[4];
      #pragma unroll
      for (int g = 0; g < 4; ++g) {
        const int r = g * 2 + jl;
        float s = bs1[r] + xv * w1c[r];
        #pragma unroll
        for (int w = 0; w < NWAVE; ++w) s += red[w][r][b];
        gate[g] = s;
      }
      const float c = gate[1] * c1s[jl][b] + gate[0] * gate[2];
      c1s[jl][b] = c;
      h1new[(size_t)(j0 + jl) * B + b] = gate[3] * tanhf(c);
    }

    ++bar;
    gbar(cnt, NWG * bar);

    if (wg == 0 && t >= 1 && t <= SEQT - 1) {
      const float* hb2 = h2old + (size_t)(wvu * 64) * B;
      const float* lwp = lw + wvu * 64;
      float p = 0.f;
      #pragma unroll 8
      for (int j = 0; j < 64; ++j) p = fmaf(lwp[j], hb2[j * B + lane], p);
      outred[wvu][lane] = p;
      __syncthreads();
      if (tid < B) {
        float o = lbv;
        #pragma unroll
        for (int s = 0; s < NWAVE; ++s) o += outred[s][tid];
        out[(size_t)tid * TT + (t - 1)] = o;
      }
      __syncthreads();
    }

    {
      const float* h1p = h1new + (size_t)kb * B;
      const float* h2p = h2old + (size_t)kb * B;
      float s0=0.f,s1=0.f,s2=0.f,s3=0.f,s4=0.f,s5=0.f,s6=0.f,s7=0.f;
      float q0=0.f,q1=0.f,q2=0.f,q3=0.f,q4=0.f,q5=0.f,q6=0.f,q7=0.f;
      #pragma unroll 4
      for (int k = 0; k < 64; ++k) {
        const float h1v = h1p[k * B + lane];
        const float h2v = h2p[k * B + lane];
        s0 = fmaf(w2p[0][k], h1v, s0); q0 = fmaf(u2p[0][k], h2v, q0);
        s1 = fmaf(w2p[1][k], h1v, s1); q1 = fmaf(u2p[1][k], h2v, q1);
        s2 = fmaf(w2p[2][k], h1v, s2); q2 = fmaf(u2p[2][k], h2v, q2);
        s3 = fmaf(w2p[3][k], h1v, s3); q3 = fmaf(u2p[3][k], h2v, q3);
        s4 = fmaf(w2p[4][k], h1v, s4); q4 = fmaf(u2p[4][k], h2v, q4);
        s5 = fmaf(w2p[5][k], h1v, s5); q5 = fmaf(u2p[5][k], h2v, q5);
        s6 = fmaf(w2p[6][k], h1v, s6); q6 = fmaf(u2p[6][k], h2v, q6);
        s7 = fmaf(w2p[7][k], h1v, s7); q7 = fmaf(u2p[7][k], h2v, q7);
      }
      red[wvu][0][lane]=s0+q0; red[wvu][1][lane]=s1+q1;
      red[wvu][2][lane]=s2+q2; red[wvu][3][lane]=s3+q3;
      red[wvu][4][lane]=s4+q4; red[wvu][5][lane]=s5+q5;
      red[wvu][6][lane]=s6+q6; red[wvu][7][lane]=s7+q7;
    }
    __syncthreads();

    if (tid < JPW * B) {
      const int jl = tid >> 6, b = tid & 63;
      float gate[4];
      #pragma unroll
      for (int g = 0; g < 4; ++g) {
        const int r = g * 2 + jl;
        float s = bs2[r];
        #pragma unroll
        for (int w = 0; w < NWAVE; ++w) s += red[w][r][b];
        gate[g] = s;
      }
      const float c = gate[1] * c2s[jl][b] + gate[0] * gate[2];
      c2s[jl][b] = c;
      h2new[(size_t)(j0 + jl) * B + b] = gate[3] * tanhf(c);
    }
    __syncthreads();

    if (t >= SEQT - 1) {
      ++bar;
      gbar(cnt, NWG * bar);
      if (wg == 0) {
        const float* hb2 = h2new + (size_t)(wvu * 64) * B;
        const float* lwp = lw + wvu * 64;
        float p = 0.f;
        #pragma unroll 8
        for (int j = 0; j < 64; ++j) p = fmaf(lwp[j], hb2[j * B + lane], p);
        outred[wvu][lane] = p;
        __syncthreads();
        if (tid < B) {
          float o = lbv;
          #pragma unroll
          for (int s = 0; s < NWAVE; ++s) o += outred[s][tid];
          out[(size_t)tid * TT + t] = o;
        }
        __syncthreads();
      }
      ++bar;
      gbar(cnt, NWG * bar);
    }
  }
}

extern "C" void kernel_launch(void* const* d_in, const int* in_sizes, int n_in,
                              void* d_out, int out_size, void* d_ws, size_t ws_size,
                              hipStream_t stream) {
  (void)in_sizes; (void)n_in; (void)out_size;
  const float* x   = (const float*)d_in[0];
  const float* W1  = (const float*)d_in[1];
  const float* bW1 = (const float*)d_in[2];
  const float* U1  = (const float*)d_in[3];
  const float* bU1 = (const float*)d_in[4];
  const float* W2  = (const float*)d_in[5];
  const float* bW2 = (const float*)d_in[6];
  const float* U2  = (const float*)d_in[7];
  const float* bU2 = (const float*)d_in[8];
  const float* lw  = (const float*)d_in[9];
  const float* lb  = (const float*)d_in[10];

  float* out = (float*)d_out;
  float* ws  = (float*)d_ws;

  if (ws_size >= (size_t)WS_TOT_F * sizeof(float)) {
    prep_ws<<<(WS_TOT_F + 255) / 256, 256, 0, stream>>>(x, U1, W2, U2, ws);
    rnn_main<<<NWG, TPB, 0, stream>>>(W1, bW1, bU1, bW2, bU2, lw, lb, out,
                                      (int*)ws, ws + WS_H1_F, ws + WS_H2_F,
                                      ws + WS_BLOB_F, ws + WS_XT_F);
  } else {
    const int nzero = 16 + 4 * HID * B;
    zero_ws<<<(nzero + TPB - 1) / TPB, TPB, 0, stream>>>(ws, nzero);
    rnn_fallback<<<NWG, TPB, 0, stream>>>(x, W1, bW1, U1, bU1,
                                          W2, bW2, U2, bU2, lw, lb, out, ws);
  }
}

// Round 6
// 14048.045 us; speedup vs baseline: 3.2329x; 1.6193x over previous
//
#include <hip/hip_runtime.h>
#include <math.h>

#define HID 512
#define B 64
#define SEQT 1024
#define FUT 16
#define TT (SEQT + FUT)
#define NWG 256
#define TPB 512
#define NWAVE 8          // TPB/64
#define JPW 2            // hidden units owned per WG = HID/NWG
#define HB (HID * B)     // one h buffer, floats
#define BLOBF 12288      // floats per WG: 4096 (phase1) + 8192 (phase2)

// ws float layout (main path):
//   [0..511]               barrier block (ints):
//                            slot[wg] at int wg   (wg<256)
//                            go       at int 320  (own cacheline)
//   [512 .. +2HB)          h1 double buffer  (float4 tiles: h4[k>>2][b][k&3])
//   [.. +2HB)              h2 double buffer  (same layout)
//   [.. +NWG*BLOBF)        rearranged weight blobs (per WG)
//   [.. +SEQT*B)           xT (x transposed to [t][b])
#define WS_H1_F   512
#define WS_H2_F   (WS_H1_F + 2 * HB)
#define WS_BLOB_F (WS_H2_F + 2 * HB)
#define WS_XT_F   (WS_BLOB_F + NWG * BLOBF)
#define WS_TOT_F  (WS_XT_F + SEQT * B)

// publish a value device-wide WITHOUT buffer_wbl2: write-through store that
// commits at the coherence point (MALL), so readers' post-inv fills hit LIC
// instead of HBM. This is the round-6 single-variable change: r1-r5 used
// __threadfence (buffer_wbl2 = L2 writeback, MALL-no-allocate -> every h
// read went to HBM at ~900cy; FETCH_SIZE showed ~1 MB/step from HBM).
__device__ inline void pub_store(float* p, float v) {
  __hip_atomic_store(p, v, __ATOMIC_RELAXED, __HIP_MEMORY_SCOPE_AGENT);
}

// ---- grid barrier v4: slot-store arrivals + leader vector poll + 1 go flag --
//  * NO __threadfence anywhere in the step path (see pub_store)
//  * release = per-thread s_waitcnt(0) (write-through stores are globally
//    visible once vmcnt retires), then flag store
//  * ONE buffer_inv per WG per barrier, BEFORE the spin (drop stale clean
//    L2 lines while we wait; nobody invalidates after `go`, so the 32 WGs
//    of an XCD share post-go L2 fills)
//  * spin with RELAXED loads (ACQUIRE-per-poll = inv per poll = L2 dead)
__device__ inline void gbar4(int* bb, int wg, int bar) {
  __builtin_amdgcn_s_waitcnt(0);   // all threads: drain own stores (at LIC)
  __syncthreads();
  const int tid  = threadIdx.x;
  const int lane = tid & 63;
  if (tid == 0) {
    __hip_atomic_store(bb + wg, bar, __ATOMIC_RELAXED, __HIP_MEMORY_SCOPE_AGENT);
    __builtin_amdgcn_fence(__ATOMIC_ACQUIRE, "agent");  // pre-spin inv
  }
  if (wg == NWG - 1 && tid < 64) {
    // leader wave: poll all 256 arrival slots (4 coherent dwords per lane)
    for (;;) {
      int a = __hip_atomic_load(bb + lane,       __ATOMIC_RELAXED, __HIP_MEMORY_SCOPE_AGENT);
      int b = __hip_atomic_load(bb + 64  + lane, __ATOMIC_RELAXED, __HIP_MEMORY_SCOPE_AGENT);
      int c = __hip_atomic_load(bb + 128 + lane, __ATOMIC_RELAXED, __HIP_MEMORY_SCOPE_AGENT);
      int d = __hip_atomic_load(bb + 192 + lane, __ATOMIC_RELAXED, __HIP_MEMORY_SCOPE_AGENT);
      if (__all(a >= bar && b >= bar && c >= bar && d >= bar)) break;
      __builtin_amdgcn_s_sleep(2);
    }
    if (lane == 0)
      __hip_atomic_store(bb + 320, bar, __ATOMIC_RELAXED, __HIP_MEMORY_SCOPE_AGENT);
  }
  if (tid == 0) {
    while (__hip_atomic_load(bb + 320, __ATOMIC_RELAXED,
                             __HIP_MEMORY_SCOPE_AGENT) < bar) {
      __builtin_amdgcn_s_sleep(2);
    }
  }
  __syncthreads();  // h loads below stay below
}

// ---------------- prep: zero state, rearrange weights, transpose x -----------
__global__ void __launch_bounds__(256) prep_ws(
    const float* __restrict__ x,
    const float* __restrict__ U1, const float* __restrict__ W2,
    const float* __restrict__ U2, float* __restrict__ ws)
{
  const int idx = blockIdx.x * blockDim.x + threadIdx.x;
  if (idx < WS_BLOB_F) {                       // barrier block + h buffers
    ws[idx] = 0.0f;
  }
  {
    const int i2 = idx - WS_BLOB_F;
    if (i2 >= 0 && i2 < NWG * BLOBF) {
      const int wg  = i2 / BLOBF;
      const int off = i2 - wg * BLOBF;
      const int j0  = wg * JPW;
      float v;
      if (off < 4096) {                        // phase1: [k*8 + r] = U1[row(r)][k]
        const int k = off >> 3, r = off & 7;
        const int row = (r >> 1) * HID + j0 + (r & 1);
        v = U1[(size_t)row * HID + k];
      } else {                                 // phase2: [k*16 + rr]
        const int o2 = off - 4096;
        const int k = o2 >> 4, rr = o2 & 15;
        const int r = rr & 7;
        const int row = (r >> 1) * HID + j0 + (r & 1);
        v = (rr < 8) ? W2[(size_t)row * HID + k] : U2[(size_t)row * HID + k];
      }
      ws[WS_BLOB_F + i2] = v;
    }
  }
  {
    const int i3 = idx - WS_XT_F;
    if (i3 >= 0 && i3 < SEQT * B) {
      const int t = i3 >> 6, b = i3 & 63;
      ws[WS_XT_F + i3] = x[(size_t)b * SEQT + t];
    }
  }
}

// ---------------- persistent 2-layer LSTM: LDS weights, float4 h -------------
__global__ void __launch_bounds__(TPB, 1) rnn_main(
    const float* __restrict__ W1, const float* __restrict__ bW1,
    const float* __restrict__ bU1,
    const float* __restrict__ bW2, const float* __restrict__ bU2,
    const float* __restrict__ lw, const float* __restrict__ lb,
    float* __restrict__ out,
    int* __restrict__ bb,
    float* __restrict__ h1b, float* __restrict__ h2b,
    const float* __restrict__ wbl, const float* __restrict__ xT)
{
  __shared__ float wlds[BLOBF];        // 48 KB persistent weight blob
  __shared__ float red[NWAVE][8][B];   // per-wave partial dots, 16 KB
  __shared__ float outred[NWAVE][B];   // output-head reduction, 2 KB
  __shared__ float c1s[JPW][B], c2s[JPW][B];
  __shared__ float w1c[8], bs1[8], bs2[8];

  const int wg   = blockIdx.x;
  const int j0   = wg * JPW;
  const int tid  = threadIdx.x;
  const int lane = tid & 63;
  const int wvu  = __builtin_amdgcn_readfirstlane(tid >> 6);

  // ---- one-time: copy this WG's weight blob into LDS ----
  {
    const float4* gsrc = (const float4*)(wbl + (size_t)wg * BLOBF);
    float4* ldst = (float4*)wlds;
    #pragma unroll
    for (int i = 0; i < BLOBF / 4 / TPB; ++i)
      ldst[i * TPB + tid] = gsrc[i * TPB + tid];
  }
  if (tid < JPW * B) { c1s[tid >> 6][lane] = 0.f; c2s[tid >> 6][lane] = 0.f; }
  if (tid < 8) {
    const int g = tid >> 1, jl = tid & 1;
    const int row = g * HID + j0 + jl;
    w1c[tid] = W1[row];
    bs1[tid] = bW1[row] + bU1[row];
    bs2[tid] = bW2[row] + bU2[row];
  }
  __syncthreads();

  const float* wl1 = wlds + wvu * 512;          // phase1 weights, this wave
  const float* wl2 = wlds + 4096 + wvu * 1024;  // phase2 weights, this wave
  const float lbv = lb[0];

  int bar = 0;
  for (int t = 0; t < TT; ++t) {
    const float* h1old = h1b + ((t + 1) & 1) * HB;
    float*       h1new = h1b + (t & 1) * HB;
    const float* h2old = h2b + ((t + 1) & 1) * HB;
    float*       h2new = h2b + (t & 1) * HB;

    // prefetch x for cell-1 (teacher region)
    float xvpref = 0.f;
    if (tid < JPW * B && t < SEQT) xvpref = xT[(size_t)t * B + lane];

    // -------- phase 1: gates1 = U1 h1(t-1) ----------------------------------
    {
      const float4* hp = (const float4*)h1old + (size_t)(wvu * 16) * B + lane;
      float4 hq[16];
      #pragma unroll
      for (int i = 0; i < 16; ++i) hq[i] = hp[i * B];
      float a[8] = {0.f,0.f,0.f,0.f,0.f,0.f,0.f,0.f};
      #pragma unroll
      for (int c = 0; c < 16; ++c) {            // k-quad within this wave's 64-k
        const float hh[4] = {hq[c].x, hq[c].y, hq[c].z, hq[c].w};
        #pragma unroll
        for (int j = 0; j < 4; ++j) {
          const float4 wA = *(const float4*)(wl1 + c * 32 + j * 8);
          const float4 wB = *(const float4*)(wl1 + c * 32 + j * 8 + 4);
          const float h = hh[j];
          a[0] = fmaf(wA.x, h, a[0]); a[1] = fmaf(wA.y, h, a[1]);
          a[2] = fmaf(wA.z, h, a[2]); a[3] = fmaf(wA.w, h, a[3]);
          a[4] = fmaf(wB.x, h, a[4]); a[5] = fmaf(wB.y, h, a[5]);
          a[6] = fmaf(wB.z, h, a[6]); a[7] = fmaf(wB.w, h, a[7]);
        }
      }
      #pragma unroll
      for (int r = 0; r < 8; ++r) red[wvu][r][lane] = a[r];
    }
    __syncthreads();

    // cell-1 elementwise (2 j's x 64 b = 128 threads)
    if (tid < JPW * B) {
      const int jl = tid >> 6, b = tid & 63;
      const float xv = (t < SEQT) ? xvpref : out[(size_t)b * TT + (t - 1)];
      float gate[4];
      #pragma unroll
      for (int g = 0; g < 4; ++g) {
        const int r = g * 2 + jl;
        float s = bs1[r] + xv * w1c[r];
        #pragma unroll
        for (int w = 0; w < NWAVE; ++w) s += red[w][r][b];
        gate[g] = s;
      }
      const float c = gate[1] * c1s[jl][b] + gate[0] * gate[2];
      c1s[jl][b] = c;
      const int j = j0 + jl;
      pub_store(&h1new[(size_t)(j >> 2) * (B * 4) + b * 4 + (j & 3)],
                gate[3] * tanhf(c));
    }

    ++bar;
    gbar4(bb, wg, bar);

    // duty WG (round-robin, never the leader WG 255): output head for t-1,
    // overlapped with the other WGs' phase 2. h2(t-1) published by barrier.
    if (wg == (t & 127) && t >= 1 && t <= SEQT - 1) {
      const float4* hb2 = (const float4*)h2old + (size_t)(wvu * 16) * B + lane;
      const float4* lw4 = (const float4*)lw + wvu * 16;
      float p = 0.f;
      #pragma unroll
      for (int i = 0; i < 16; ++i) {
        const float4 hv = hb2[i * B];
        const float4 wv = lw4[i];
        p = fmaf(wv.x, hv.x, p); p = fmaf(wv.y, hv.y, p);
        p = fmaf(wv.z, hv.z, p); p = fmaf(wv.w, hv.w, p);
      }
      outred[wvu][lane] = p;
      __syncthreads();
      if (tid < B) {
        float o = lbv;
        #pragma unroll
        for (int s = 0; s < NWAVE; ++s) o += outred[s][tid];
        pub_store(&out[(size_t)tid * TT + (t - 1)], o);
      }
      __syncthreads();
    }

    // -------- phase 2: gates2 = W2 h1(t) + U2 h2(t-1) ------------------------
    {
      const float4* pp4 = (const float4*)h1new + (size_t)(wvu * 16) * B + lane;
      const float4* qq4 = (const float4*)h2old + (size_t)(wvu * 16) * B + lane;
      float4 P[16], Q[16];
      #pragma unroll
      for (int i = 0; i < 16; ++i) P[i] = pp4[i * B];
      #pragma unroll
      for (int i = 0; i < 16; ++i) Q[i] = qq4[i * B];
      float a[8] = {0.f,0.f,0.f,0.f,0.f,0.f,0.f,0.f};
      #pragma unroll
      for (int c = 0; c < 16; ++c) {
        const float hp_[4] = {P[c].x, P[c].y, P[c].z, P[c].w};
        const float hq_[4] = {Q[c].x, Q[c].y, Q[c].z, Q[c].w};
        #pragma unroll
        for (int j = 0; j < 4; ++j) {
          const float4 w0 = *(const float4*)(wl2 + c * 64 + j * 16);
          const float4 w1 = *(const float4*)(wl2 + c * 64 + j * 16 + 4);
          const float4 w2 = *(const float4*)(wl2 + c * 64 + j * 16 + 8);
          const float4 w3 = *(const float4*)(wl2 + c * 64 + j * 16 + 12);
          const float hp1 = hp_[j], hq1 = hq_[j];
          a[0] = fmaf(w0.x, hp1, a[0]); a[1] = fmaf(w0.y, hp1, a[1]);
          a[2] = fmaf(w0.z, hp1, a[2]); a[3] = fmaf(w0.w, hp1, a[3]);
          a[4] = fmaf(w1.x, hp1, a[4]); a[5] = fmaf(w1.y, hp1, a[5]);
          a[6] = fmaf(w1.z, hp1, a[6]); a[7] = fmaf(w1.w, hp1, a[7]);
          a[0] = fmaf(w2.x, hq1, a[0]); a[1] = fmaf(w2.y, hq1, a[1]);
          a[2] = fmaf(w2.z, hq1, a[2]); a[3] = fmaf(w2.w, hq1, a[3]);
          a[4] = fmaf(w3.x, hq1, a[4]); a[5] = fmaf(w3.y, hq1, a[5]);
          a[6] = fmaf(w3.z, hq1, a[6]); a[7] = fmaf(w3.w, hq1, a[7]);
        }
      }
      #pragma unroll
      for (int r = 0; r < 8; ++r) red[wvu][r][lane] = a[r];
    }
    __syncthreads();

    // cell-2 elementwise
    if (tid < JPW * B) {
      const int jl = tid >> 6, b = tid & 63;
      float gate[4];
      #pragma unroll
      for (int g = 0; g < 4; ++g) {
        const int r = g * 2 + jl;
        float s = bs2[r];
        #pragma unroll
        for (int w = 0; w < NWAVE; ++w) s += red[w][r][b];
        gate[g] = s;
      }
      const float c = gate[1] * c2s[jl][b] + gate[0] * gate[2];
      c2s[jl][b] = c;
      const int j = j0 + jl;
      pub_store(&h2new[(size_t)(j >> 2) * (B * 4) + b * 4 + (j & 3)],
                gate[3] * tanhf(c));
    }
    __syncthreads();  // protect red[] before next step's phase-1 writes

    // Autoregressive region: out(t) must be globally visible before phase1(t+1)
    if (t >= SEQT - 1) {
      ++bar;
      gbar4(bb, wg, bar);
      if (wg == 0) {
        const float4* hb2 = (const float4*)h2new + (size_t)(wvu * 16) * B + lane;
        const float4* lw4 = (const float4*)lw + wvu * 16;
        float p = 0.f;
        #pragma unroll
        for (int i = 0; i < 16; ++i) {
          const float4 hv = hb2[i * B];
          const float4 wv = lw4[i];
          p = fmaf(wv.x, hv.x, p); p = fmaf(wv.y, hv.y, p);
          p = fmaf(wv.z, hv.z, p); p = fmaf(wv.w, hv.w, p);
        }
        outred[wvu][lane] = p;
        __syncthreads();
        if (tid < B) {
          float o = lbv;
          #pragma unroll
          for (int s = 0; s < NWAVE; ++s) o += outred[s][tid];
          pub_store(&out[(size_t)tid * TT + t], o);
        }
        __syncthreads();
      }
      ++bar;
      gbar4(bb, wg, bar);
    }
  }
}

// =================== fallback path (round-0 kernel, known correct) ===========
__device__ inline void gbar(int* cnt, int target) {
  __syncthreads();
  if (threadIdx.x == 0) {
    __threadfence();
    __hip_atomic_fetch_add(cnt, 1, __ATOMIC_RELEASE, __HIP_MEMORY_SCOPE_AGENT);
    while (__hip_atomic_load(cnt, __ATOMIC_ACQUIRE, __HIP_MEMORY_SCOPE_AGENT) < target) {
      __builtin_amdgcn_s_sleep(2);
    }
  }
  __syncthreads();
}

__global__ void __launch_bounds__(TPB) zero_ws(float* ws, int n) {
  int i = blockIdx.x * blockDim.x + threadIdx.x;
  if (i < n) ws[i] = 0.0f;
}

__global__ void __launch_bounds__(TPB) rnn_fallback(
    const float* __restrict__ x,
    const float* __restrict__ W1, const float* __restrict__ bW1,
    const float* __restrict__ U1, const float* __restrict__ bU1,
    const float* __restrict__ W2, const float* __restrict__ bW2,
    const float* __restrict__ U2, const float* __restrict__ bU2,
    const float* __restrict__ lw, const float* __restrict__ lb,
    float* out, float* ws)
{
  __shared__ float red[NWAVE][8][B];
  __shared__ float outred[NWAVE][B];
  __shared__ float c1s[JPW][B], c2s[JPW][B];
  __shared__ float w1c[8], bs1[8], bs2[8];

  int* cnt   = (int*)ws;
  float* h1b = ws + 16;
  float* h2b = h1b + 2 * HB;

  const int wg   = blockIdx.x;
  const int j0   = wg * JPW;
  const int tid  = threadIdx.x;
  const int lane = tid & 63;
  const int wvu  = __builtin_amdgcn_readfirstlane(tid >> 6);
  const int kb   = wvu << 6;

  if (tid < JPW * B) { c1s[tid >> 6][lane] = 0.f; c2s[tid >> 6][lane] = 0.f; }
  if (tid < 8) {
    const int g = tid >> 1, jl = tid & 1;
    const int row = g * HID + j0 + jl;
    w1c[tid] = W1[row];
    bs1[tid] = bW1[row] + bU1[row];
    bs2[tid] = bW2[row] + bU2[row];
  }
  __syncthreads();

  const float* u1p[8]; const float* w2p[8]; const float* u2p[8];
  #pragma unroll
  for (int r = 0; r < 8; ++r) {
    const int row = (r >> 1) * HID + j0 + (r & 1);
    u1p[r] = U1 + (size_t)row * HID + kb;
    w2p[r] = W2 + (size_t)row * HID + kb;
    u2p[r] = U2 + (size_t)row * HID + kb;
  }
  const float lbv = lb[0];

  int bar = 0;
  for (int t = 0; t < TT; ++t) {
    const float* h1old = h1b + ((t + 1) & 1) * HB;
    float*       h1new = h1b + (t & 1) * HB;
    const float* h2old = h2b + ((t + 1) & 1) * HB;
    float*       h2new = h2b + (t & 1) * HB;

    {
      const float* hp = h1old + (size_t)kb * B;
      float a0=0.f,a1=0.f,a2=0.f,a3=0.f,a4=0.f,a5=0.f,a6=0.f,a7=0.f;
      #pragma unroll 8
      for (int k = 0; k < 64; ++k) {
        const float hv = hp[k * B + lane];
        a0 = fmaf(u1p[0][k], hv, a0); a1 = fmaf(u1p[1][k], hv, a1);
        a2 = fmaf(u1p[2][k], hv, a2); a3 = fmaf(u1p[3][k], hv, a3);
        a4 = fmaf(u1p[4][k], hv, a4); a5 = fmaf(u1p[5][k], hv, a5);
        a6 = fmaf(u1p[6][k], hv, a6); a7 = fmaf(u1p[7][k], hv, a7);
      }
      red[wvu][0][lane]=a0; red[wvu][1][lane]=a1; red[wvu][2][lane]=a2; red[wvu][3][lane]=a3;
      red[wvu][4][lane]=a4; red[wvu][5][lane]=a5; red[wvu][6][lane]=a6; red[wvu][7][lane]=a7;
    }
    __syncthreads();

    if (tid < JPW * B) {
      const int jl = tid >> 6, b = tid & 63;
      const float xv = (t < SEQT) ? x[(size_t)b * SEQT + t]
                                  : out[(size_t)b * TT + (t - 1)];
      float gate[4];
      #pragma unroll
      for (int g = 0; g < 4; ++g) {
        const int r = g * 2 + jl;
        float s = bs1[r] + xv * w1c[r];
        #pragma unroll
        for (int w = 0; w < NWAVE; ++w) s += red[w][r][b];
        gate[g] = s;
      }
      const float c = gate[1] * c1s[jl][b] + gate[0] * gate[2];
      c1s[jl][b] = c;
      h1new[(size_t)(j0 + jl) * B + b] = gate[3] * tanhf(c);
    }

    ++bar;
    gbar(cnt, NWG * bar);

    if (wg == 0 && t >= 1 && t <= SEQT - 1) {
      const float* hb2 = h2old + (size_t)(wvu * 64) * B;
      const float* lwp = lw + wvu * 64;
      float p = 0.f;
      #pragma unroll 8
      for (int j = 0; j < 64; ++j) p = fmaf(lwp[j], hb2[j * B + lane], p);
      outred[wvu][lane] = p;
      __syncthreads();
      if (tid < B) {
        float o = lbv;
        #pragma unroll
        for (int s = 0; s < NWAVE; ++s) o += outred[s][tid];
        out[(size_t)tid * TT + (t - 1)] = o;
      }
      __syncthreads();
    }

    {
      const float* h1p = h1new + (size_t)kb * B;
      const float* h2p = h2old + (size_t)kb * B;
      float s0=0.f,s1=0.f,s2=0.f,s3=0.f,s4=0.f,s5=0.f,s6=0.f,s7=0.f;
      float q0=0.f,q1=0.f,q2=0.f,q3=0.f,q4=0.f,q5=0.f,q6=0.f,q7=0.f;
      #pragma unroll 4
      for (int k = 0; k < 64; ++k) {
        const float h1v = h1p[k * B + lane];
        const float h2v = h2p[k * B + lane];
        s0 = fmaf(w2p[0][k], h1v, s0); q0 = fmaf(u2p[0][k], h2v, q0);
        s1 = fmaf(w2p[1][k], h1v, s1); q1 = fmaf(u2p[1][k], h2v, q1);
        s2 = fmaf(w2p[2][k], h1v, s2); q2 = fmaf(u2p[2][k], h2v, q2);
        s3 = fmaf(w2p[3][k], h1v, s3); q3 = fmaf(u2p[3][k], h2v, q3);
        s4 = fmaf(w2p[4][k], h1v, s4); q4 = fmaf(u2p[4][k], h2v, q4);
        s5 = fmaf(w2p[5][k], h1v, s5); q5 = fmaf(u2p[5][k], h2v, q5);
        s6 = fmaf(w2p[6][k], h1v, s6); q6 = fmaf(u2p[6][k], h2v, q6);
        s7 = fmaf(w2p[7][k], h1v, s7); q7 = fmaf(u2p[7][k], h2v, q7);
      }
      red[wvu][0][lane]=s0+q0; red[wvu][1][lane]=s1+q1;
      red[wvu][2][lane]=s2+q2; red[wvu][3][lane]=s3+q3;
      red[wvu][4][lane]=s4+q4; red[wvu][5][lane]=s5+q5;
      red[wvu][6][lane]=s6+q6; red[wvu][7][lane]=s7+q7;
    }
    __syncthreads();

    if (tid < JPW * B) {
      const int jl = tid >> 6, b = tid & 63;
      float gate[4];
      #pragma unroll
      for (int g = 0; g < 4; ++g) {
        const int r = g * 2 + jl;
        float s = bs2[r];
        #pragma unroll
        for (int w = 0; w < NWAVE; ++w) s += red[w][r][b];
        gate[g] = s;
      }
      const float c = gate[1] * c2s[jl][b] + gate[0] * gate[2];
      c2s[jl][b] = c;
      h2new[(size_t)(j0 + jl) * B + b] = gate[3] * tanhf(c);
    }
    __syncthreads();

    if (t >= SEQT - 1) {
      ++bar;
      gbar(cnt, NWG * bar);
      if (wg == 0) {
        const float* hb2 = h2new + (size_t)(wvu * 64) * B;
        const float* lwp = lw + wvu * 64;
        float p = 0.f;
        #pragma unroll 8
        for (int j = 0; j < 64; ++j) p = fmaf(lwp[j], hb2[j * B + lane], p);
        outred[wvu][lane] = p;
        __syncthreads();
        if (tid < B) {
          float o = lbv;
          #pragma unroll
          for (int s = 0; s < NWAVE; ++s) o += outred[s][tid];
          out[(size_t)tid * TT + t] = o;
        }
        __syncthreads();
      }
      ++bar;
      gbar(cnt, NWG * bar);
    }
  }
}

extern "C" void kernel_launch(void* const* d_in, const int* in_sizes, int n_in,
                              void* d_out, int out_size, void* d_ws, size_t ws_size,
                              hipStream_t stream) {
  (void)in_sizes; (void)n_in; (void)out_size;
  const float* x   = (const float*)d_in[0];
  const float* W1  = (const float*)d_in[1];
  const float* bW1 = (const float*)d_in[2];
  const float* U1  = (const float*)d_in[3];
  const float* bU1 = (const float*)d_in[4];
  const float* W2  = (const float*)d_in[5];
  const float* bW2 = (const float*)d_in[6];
  const float* U2  = (const float*)d_in[7];
  const float* bU2 = (const float*)d_in[8];
  const float* lw  = (const float*)d_in[9];
  const float* lb  = (const float*)d_in[10];

  float* out = (float*)d_out;
  float* ws  = (float*)d_ws;

  if (ws_size >= (size_t)WS_TOT_F * sizeof(float)) {
    prep_ws<<<(WS_TOT_F + 255) / 256, 256, 0, stream>>>(x, U1, W2, U2, ws);
    rnn_main<<<NWG, TPB, 0, stream>>>(W1, bW1, bU1, bW2, bU2, lw, lb, out,
                                      (int*)ws, ws + WS_H1_F, ws + WS_H2_F,
                                      ws + WS_BLOB_F, ws + WS_XT_F);
  } else {
    const int nzero = 16 + 4 * HID * B;
    zero_ws<<<(nzero + TPB - 1) / TPB, TPB, 0, stream>>>(ws, nzero);
    rnn_fallback<<<NWG, TPB, 0, stream>>>(x, W1, bW1, U1, bU1,
                                          W2, bW2, U2, bU2, lw, lb, out, ws);
  }
}

// Round 7
// 12336.014 us; speedup vs baseline: 3.6815x; 1.1388x over previous
//
#include <hip/hip_runtime.h>
#include <math.h>

#define HID 512
#define B 64
#define SEQT 1024
#define FUT 16
#define TT (SEQT + FUT)
#define NWG 256
#define TPB 512          // fallback path block size
#define TPB1 1024        // main kernel block size (16 waves, 4/SIMD)
#define NWAVE1 16
#define JPW 2            // hidden units owned per WG = HID/NWG
#define HB (HID * B)     // one h buffer, floats
#define BLOBF 12288      // floats per WG: 4096 (phase1) + 8192 (phase2)

// ws float layout (main path):
//   [0..511]               barrier block (ints):
//                            slot[wg] at int wg   (wg<256)
//                            go       at int 320  (own cacheline)
//   [512 .. +2HB)          h1 double buffer  (float4 tiles: h4[k>>2][b][k&3])
//   [.. +2HB)              h2 double buffer  (same layout)
//   [.. +NWG*BLOBF)        rearranged weight blobs (per WG)
//   [.. +SEQT*B)           xT (x transposed to [t][b])
#define WS_H1_F   512
#define WS_H2_F   (WS_H1_F + 2 * HB)
#define WS_BLOB_F (WS_H2_F + 2 * HB)
#define WS_XT_F   (WS_BLOB_F + NWG * BLOBF)
#define WS_TOT_F  (WS_XT_F + SEQT * B)

// publish h device-wide WITHOUT buffer_wbl2 (r6 win: wbl2 writeback pushed h
// past the MALL -> every post-barrier read paid HBM latency).
__device__ inline void pub_store(float* p, float v) {
  __hip_atomic_store(p, v, __ATOMIC_RELAXED, __HIP_MEMORY_SCOPE_AGENT);
}

// ---- grid barrier v4 (unchanged from r6): slot stores + leader poll + go ----
__device__ inline void gbar4(int* bb, int wg, int bar) {
  __builtin_amdgcn_s_waitcnt(0);   // all threads: drain own stores
  __syncthreads();
  const int tid  = threadIdx.x;
  const int lane = tid & 63;
  if (tid == 0) {
    __hip_atomic_store(bb + wg, bar, __ATOMIC_RELAXED, __HIP_MEMORY_SCOPE_AGENT);
    __builtin_amdgcn_fence(__ATOMIC_ACQUIRE, "agent");  // pre-spin inv, once
  }
  if (wg == NWG - 1 && tid < 64) {
    for (;;) {
      int a = __hip_atomic_load(bb + lane,       __ATOMIC_RELAXED, __HIP_MEMORY_SCOPE_AGENT);
      int b = __hip_atomic_load(bb + 64  + lane, __ATOMIC_RELAXED, __HIP_MEMORY_SCOPE_AGENT);
      int c = __hip_atomic_load(bb + 128 + lane, __ATOMIC_RELAXED, __HIP_MEMORY_SCOPE_AGENT);
      int d = __hip_atomic_load(bb + 192 + lane, __ATOMIC_RELAXED, __HIP_MEMORY_SCOPE_AGENT);
      if (__all(a >= bar && b >= bar && c >= bar && d >= bar)) break;
      __builtin_amdgcn_s_sleep(2);
    }
    if (lane == 0)
      __hip_atomic_store(bb + 320, bar, __ATOMIC_RELAXED, __HIP_MEMORY_SCOPE_AGENT);
  }
  if (tid == 0) {
    while (__hip_atomic_load(bb + 320, __ATOMIC_RELAXED,
                             __HIP_MEMORY_SCOPE_AGENT) < bar) {
      __builtin_amdgcn_s_sleep(2);
    }
  }
  __syncthreads();
}

// ---------------- prep: zero state, rearrange weights, transpose x -----------
__global__ void __launch_bounds__(256) prep_ws(
    const float* __restrict__ x,
    const float* __restrict__ U1, const float* __restrict__ W2,
    const float* __restrict__ U2, float* __restrict__ ws)
{
  const int idx = blockIdx.x * blockDim.x + threadIdx.x;
  if (idx < WS_BLOB_F) {                       // barrier block + h buffers
    ws[idx] = 0.0f;
  }
  {
    const int i2 = idx - WS_BLOB_F;
    if (i2 >= 0 && i2 < NWG * BLOBF) {
      const int wg  = i2 / BLOBF;
      const int off = i2 - wg * BLOBF;
      const int j0  = wg * JPW;
      float v;
      if (off < 4096) {                        // phase1: [k*8 + r] = U1[row(r)][k]
        const int k = off >> 3, r = off & 7;
        const int row = (r >> 1) * HID + j0 + (r & 1);
        v = U1[(size_t)row * HID + k];
      } else {                                 // phase2: [k*16 + rr]
        const int o2 = off - 4096;
        const int k = o2 >> 4, rr = o2 & 15;
        const int r = rr & 7;
        const int row = (r >> 1) * HID + j0 + (r & 1);
        v = (rr < 8) ? W2[(size_t)row * HID + k] : U2[(size_t)row * HID + k];
      }
      ws[WS_BLOB_F + i2] = v;
    }
  }
  {
    const int i3 = idx - WS_XT_F;
    if (i3 >= 0 && i3 < SEQT * B) {
      const int t = i3 >> 6, b = i3 & 63;
      ws[WS_XT_F + i3] = x[(size_t)b * SEQT + t];
    }
  }
}

// -------- persistent 2-layer LSTM: LDS weights, register-carried h1 ----------
// 16 waves/WG (4/SIMD). Wave wvu owns k-chunk [wvu*32, wvu*32+32).
// phase1 uses H1 registers (h1(t-1), carried from last step's phase2 load) ->
// NO global loads before the barrier. phase2 loads H1<-h1(t), Q<-h2(t-1):
// the only post-barrier global reads (16 dwordx4/wave).
__global__ void __launch_bounds__(TPB1, 1) rnn_main(
    const float* __restrict__ W1, const float* __restrict__ bW1,
    const float* __restrict__ bU1,
    const float* __restrict__ bW2, const float* __restrict__ bU2,
    const float* __restrict__ lw, const float* __restrict__ lb,
    float* __restrict__ out,
    int* __restrict__ bb,
    float* __restrict__ h1b, float* __restrict__ h2b,
    const float* __restrict__ wbl, const float* __restrict__ xT)
{
  __shared__ float wlds[BLOBF];         // 48 KB persistent weight blob
  __shared__ float red[NWAVE1][8][B];   // per-wave partial dots, 32 KB
  __shared__ float outred[NWAVE1][B];   // output-head reduction, 4 KB
  __shared__ float c1s[JPW][B], c2s[JPW][B];
  __shared__ float w1c[8], bs1[8], bs2[8];

  const int wg   = blockIdx.x;
  const int j0   = wg * JPW;
  const int tid  = threadIdx.x;
  const int lane = tid & 63;
  const int wvu  = __builtin_amdgcn_readfirstlane(tid >> 6);

  // ---- one-time: copy this WG's weight blob into LDS ----
  {
    const float4* gsrc = (const float4*)(wbl + (size_t)wg * BLOBF);
    float4* ldst = (float4*)wlds;
    #pragma unroll
    for (int i = 0; i < BLOBF / 4 / TPB1; ++i)
      ldst[i * TPB1 + tid] = gsrc[i * TPB1 + tid];
  }
  if (tid < JPW * B) { c1s[tid >> 6][lane] = 0.f; c2s[tid >> 6][lane] = 0.f; }
  if (tid < 8) {
    const int g = tid >> 1, jl = tid & 1;
    const int row = g * HID + j0 + jl;
    w1c[tid] = W1[row];
    bs1[tid] = bW1[row] + bU1[row];
    bs2[tid] = bW2[row] + bU2[row];
  }
  __syncthreads();

  const float* wl1 = wlds + wvu * 256;          // phase1 weights, this wave
  const float* wl2 = wlds + 4096 + wvu * 512;   // phase2 weights, this wave
  const float lbv = lb[0];

  float4 H1[8], Q[8];                           // h1 carry + h2old staging
  #pragma unroll
  for (int i = 0; i < 8; ++i) H1[i] = make_float4(0.f, 0.f, 0.f, 0.f);

  int bar = 0;
  for (int t = 0; t < TT; ++t) {
    float*       h1new = h1b + (t & 1) * HB;
    const float* h2old = h2b + ((t + 1) & 1) * HB;
    float*       h2new = h2b + (t & 1) * HB;

    // prefetch x for cell-1 (teacher region)
    float xvpref = 0.f;
    if (tid < JPW * B && t < SEQT) xvpref = xT[(size_t)t * B + lane];

    // -------- phase 1: gates1 = U1 h1(t-1), h1(t-1) in H1 registers ---------
    {
      float a[8] = {0.f,0.f,0.f,0.f,0.f,0.f,0.f,0.f};
      #pragma unroll
      for (int c = 0; c < 8; ++c) {             // 8 k-quads in this wave's 32-k
        const float hh[4] = {H1[c].x, H1[c].y, H1[c].z, H1[c].w};
        #pragma unroll
        for (int j = 0; j < 4; ++j) {
          const float4 wA = *(const float4*)(wl1 + c * 32 + j * 8);
          const float4 wB = *(const float4*)(wl1 + c * 32 + j * 8 + 4);
          const float h = hh[j];
          a[0] = fmaf(wA.x, h, a[0]); a[1] = fmaf(wA.y, h, a[1]);
          a[2] = fmaf(wA.z, h, a[2]); a[3] = fmaf(wA.w, h, a[3]);
          a[4] = fmaf(wB.x, h, a[4]); a[5] = fmaf(wB.y, h, a[5]);
          a[6] = fmaf(wB.z, h, a[6]); a[7] = fmaf(wB.w, h, a[7]);
        }
      }
      #pragma unroll
      for (int r = 0; r < 8; ++r) red[wvu][r][lane] = a[r];
    }
    __syncthreads();

    // cell-1 elementwise (2 j's x 64 b = 128 threads)
    if (tid < JPW * B) {
      const int jl = tid >> 6, b = tid & 63;
      const float xv = (t < SEQT) ? xvpref : out[(size_t)b * TT + (t - 1)];
      float gate[4];
      #pragma unroll
      for (int g = 0; g < 4; ++g) {
        const int r = g * 2 + jl;
        float s = bs1[r] + xv * w1c[r];
        #pragma unroll
        for (int w = 0; w < NWAVE1; ++w) s += red[w][r][b];
        gate[g] = s;
      }
      const float c = gate[1] * c1s[jl][b] + gate[0] * gate[2];
      c1s[jl][b] = c;
      const int j = j0 + jl;
      pub_store(&h1new[(size_t)(j >> 2) * (B * 4) + b * 4 + (j & 3)],
                gate[3] * tanhf(c));
    }

    ++bar;
    gbar4(bb, wg, bar);

    // duty WG (round-robin): output head for t-1, overlapped with phase 2
    if (wg == (t & 127) && t >= 1 && t <= SEQT - 1) {
      const float4* hb2 = (const float4*)h2old + (size_t)(wvu * 8) * B + lane;
      const float4* lw4 = (const float4*)lw + wvu * 8;
      float p = 0.f;
      #pragma unroll
      for (int i = 0; i < 8; ++i) {
        const float4 hv = hb2[i * B];
        const float4 wv = lw4[i];
        p = fmaf(wv.x, hv.x, p); p = fmaf(wv.y, hv.y, p);
        p = fmaf(wv.z, hv.z, p); p = fmaf(wv.w, hv.w, p);
      }
      outred[wvu][lane] = p;
      __syncthreads();
      if (tid < B) {
        float o = lbv;
        #pragma unroll
        for (int s = 0; s < NWAVE1; ++s) o += outred[s][tid];
        pub_store(&out[(size_t)tid * TT + (t - 1)], o);
      }
      __syncthreads();
    }

    // -------- phase 2: gates2 = W2 h1(t) + U2 h2(t-1) ------------------------
    // H1 <- h1(t) (kept for next step's phase 1), Q <- h2(t-1)
    {
      const float4* pp4 = (const float4*)h1new + (size_t)(wvu * 8) * B + lane;
      const float4* qq4 = (const float4*)h2old + (size_t)(wvu * 8) * B + lane;
      #pragma unroll
      for (int i = 0; i < 8; ++i) H1[i] = pp4[i * B];
      #pragma unroll
      for (int i = 0; i < 8; ++i) Q[i] = qq4[i * B];
      float a[8] = {0.f,0.f,0.f,0.f,0.f,0.f,0.f,0.f};
      #pragma unroll
      for (int c = 0; c < 8; ++c) {
        const float hp_[4] = {H1[c].x, H1[c].y, H1[c].z, H1[c].w};
        const float hq_[4] = {Q[c].x, Q[c].y, Q[c].z, Q[c].w};
        #pragma unroll
        for (int j = 0; j < 4; ++j) {
          const float4 w0 = *(const float4*)(wl2 + c * 64 + j * 16);
          const float4 w1 = *(const float4*)(wl2 + c * 64 + j * 16 + 4);
          const float4 w2 = *(const float4*)(wl2 + c * 64 + j * 16 + 8);
          const float4 w3 = *(const float4*)(wl2 + c * 64 + j * 16 + 12);
          const float hp1 = hp_[j], hq1 = hq_[j];
          a[0] = fmaf(w0.x, hp1, a[0]); a[1] = fmaf(w0.y, hp1, a[1]);
          a[2] = fmaf(w0.z, hp1, a[2]); a[3] = fmaf(w0.w, hp1, a[3]);
          a[4] = fmaf(w1.x, hp1, a[4]); a[5] = fmaf(w1.y, hp1, a[5]);
          a[6] = fmaf(w1.z, hp1, a[6]); a[7] = fmaf(w1.w, hp1, a[7]);
          a[0] = fmaf(w2.x, hq1, a[0]); a[1] = fmaf(w2.y, hq1, a[1]);
          a[2] = fmaf(w2.z, hq1, a[2]); a[3] = fmaf(w2.w, hq1, a[3]);
          a[4] = fmaf(w3.x, hq1, a[4]); a[5] = fmaf(w3.y, hq1, a[5]);
          a[6] = fmaf(w3.z, hq1, a[6]); a[7] = fmaf(w3.w, hq1, a[7]);
        }
      }
      #pragma unroll
      for (int r = 0; r < 8; ++r) red[wvu][r][lane] = a[r];
    }
    __syncthreads();

    // cell-2 elementwise
    if (tid < JPW * B) {
      const int jl = tid >> 6, b = tid & 63;
      float gate[4];
      #pragma unroll
      for (int g = 0; g < 4; ++g) {
        const int r = g * 2 + jl;
        float s = bs2[r];
        #pragma unroll
        for (int w = 0; w < NWAVE1; ++w) s += red[w][r][b];
        gate[g] = s;
      }
      const float c = gate[1] * c2s[jl][b] + gate[0] * gate[2];
      c2s[jl][b] = c;
      const int j = j0 + jl;
      pub_store(&h2new[(size_t)(j >> 2) * (B * 4) + b * 4 + (j & 3)],
                gate[3] * tanhf(c));
    }
    __syncthreads();  // protect red[] before next step's phase-1 writes

    // Autoregressive region: out(t) must be globally visible before phase1(t+1)
    if (t >= SEQT - 1) {
      ++bar;
      gbar4(bb, wg, bar);
      if (wg == 0) {
        const float4* hb2 = (const float4*)h2new + (size_t)(wvu * 8) * B + lane;
        const float4* lw4 = (const float4*)lw + wvu * 8;
        float p = 0.f;
        #pragma unroll
        for (int i = 0; i < 8; ++i) {
          const float4 hv = hb2[i * B];
          const float4 wv = lw4[i];
          p = fmaf(wv.x, hv.x, p); p = fmaf(wv.y, hv.y, p);
          p = fmaf(wv.z, hv.z, p); p = fmaf(wv.w, hv.w, p);
        }
        outred[wvu][lane] = p;
        __syncthreads();
        if (tid < B) {
          float o = lbv;
          #pragma unroll
          for (int s = 0; s < NWAVE1; ++s) o += outred[s][tid];
          pub_store(&out[(size_t)tid * TT + t], o);
        }
        __syncthreads();
      }
      ++bar;
      gbar4(bb, wg, bar);
    }
  }
}

// =================== fallback path (round-0 kernel, known correct) ===========
__device__ inline void gbar(int* cnt, int target) {
  __syncthreads();
  if (threadIdx.x == 0) {
    __threadfence();
    __hip_atomic_fetch_add(cnt, 1, __ATOMIC_RELEASE, __HIP_MEMORY_SCOPE_AGENT);
    while (__hip_atomic_load(cnt, __ATOMIC_ACQUIRE, __HIP_MEMORY_SCOPE_AGENT) < target) {
      __builtin_amdgcn_s_sleep(2);
    }
  }
  __syncthreads();
}

__global__ void __launch_bounds__(TPB) zero_ws(float* ws, int n) {
  int i = blockIdx.x * blockDim.x + threadIdx.x;
  if (i < n) ws[i] = 0.0f;
}

__global__ void __launch_bounds__(TPB) rnn_fallback(
    const float* __restrict__ x,
    const float* __restrict__ W1, const float* __restrict__ bW1,
    const float* __restrict__ U1, const float* __restrict__ bU1,
    const float* __restrict__ W2, const float* __restrict__ bW2,
    const float* __restrict__ U2, const float* __restrict__ bU2,
    const float* __restrict__ lw, const float* __restrict__ lb,
    float* out, float* ws)
{
  __shared__ float red[8][8][B];
  __shared__ float outred[8][B];
  __shared__ float c1s[JPW][B], c2s[JPW][B];
  __shared__ float w1c[8], bs1[8], bs2[8];

  int* cnt   = (int*)ws;
  float* h1b = ws + 16;
  float* h2b = h1b + 2 * HB;

  const int wg   = blockIdx.x;
  const int j0   = wg * JPW;
  const int tid  = threadIdx.x;
  const int lane = tid & 63;
  const int wvu  = __builtin_amdgcn_readfirstlane(tid >> 6);
  const int kb   = wvu << 6;

  if (tid < JPW * B) { c1s[tid >> 6][lane] = 0.f; c2s[tid >> 6][lane] = 0.f; }
  if (tid < 8) {
    const int g = tid >> 1, jl = tid & 1;
    const int row = g * HID + j0 + jl;
    w1c[tid] = W1[row];
    bs1[tid] = bW1[row] + bU1[row];
    bs2[tid] = bW2[row] + bU2[row];
  }
  __syncthreads();

  const float* u1p[8]; const float* w2p[8]; const float* u2p[8];
  #pragma unroll
  for (int r = 0; r < 8; ++r) {
    const int row = (r >> 1) * HID + j0 + (r & 1);
    u1p[r] = U1 + (size_t)row * HID + kb;
    w2p[r] = W2 + (size_t)row * HID + kb;
    u2p[r] = U2 + (size_t)row * HID + kb;
  }
  const float lbv = lb[0];

  int bar = 0;
  for (int t = 0; t < TT; ++t) {
    const float* h1old = h1b + ((t + 1) & 1) * HB;
    float*       h1new = h1b + (t & 1) * HB;
    const float* h2old = h2b + ((t + 1) & 1) * HB;
    float*       h2new = h2b + (t & 1) * HB;

    {
      const float* hp = h1old + (size_t)kb * B;
      float a0=0.f,a1=0.f,a2=0.f,a3=0.f,a4=0.f,a5=0.f,a6=0.f,a7=0.f;
      #pragma unroll 8
      for (int k = 0; k < 64; ++k) {
        const float hv = hp[k * B + lane];
        a0 = fmaf(u1p[0][k], hv, a0); a1 = fmaf(u1p[1][k], hv, a1);
        a2 = fmaf(u1p[2][k], hv, a2); a3 = fmaf(u1p[3][k], hv, a3);
        a4 = fmaf(u1p[4][k], hv, a4); a5 = fmaf(u1p[5][k], hv, a5);
        a6 = fmaf(u1p[6][k], hv, a6); a7 = fmaf(u1p[7][k], hv, a7);
      }
      red[wvu][0][lane]=a0; red[wvu][1][lane]=a1; red[wvu][2][lane]=a2; red[wvu][3][lane]=a3;
      red[wvu][4][lane]=a4; red[wvu][5][lane]=a5; red[wvu][6][lane]=a6; red[wvu][7][lane]=a7;
    }
    __syncthreads();

    if (tid < JPW * B) {
      const int jl = tid >> 6, b = tid & 63;
      const float xv = (t < SEQT) ? x[(size_t)b * SEQT + t]
                                  : out[(size_t)b * TT + (t - 1)];
      float gate[4];
      #pragma unroll
      for (int g = 0; g < 4; ++g) {
        const int r = g * 2 + jl;
        float s = bs1[r] + xv * w1c[r];
        #pragma unroll
        for (int w = 0; w < 8; ++w) s += red[w][r][b];
        gate[g] = s;
      }
      const float c = gate[1] * c1s[jl][b] + gate[0] * gate[2];
      c1s[jl][b] = c;
      h1new[(size_t)(j0 + jl) * B + b] = gate[3] * tanhf(c);
    }

    ++bar;
    gbar(cnt, NWG * bar);

    if (wg == 0 && t >= 1 && t <= SEQT - 1) {
      const float* hb2 = h2old + (size_t)(wvu * 64) * B;
      const float* lwp = lw + wvu * 64;
      float p = 0.f;
      #pragma unroll 8
      for (int j = 0; j < 64; ++j) p = fmaf(lwp[j], hb2[j * B + lane], p);
      outred[wvu][lane] = p;
      __syncthreads();
      if (tid < B) {
        float o = lbv;
        #pragma unroll
        for (int s = 0; s < 8; ++s) o += outred[s][tid];
        out[(size_t)tid * TT + (t - 1)] = o;
      }
      __syncthreads();
    }

    {
      const float* h1p = h1new + (size_t)kb * B;
      const float* h2p = h2old + (size_t)kb * B;
      float s0=0.f,s1=0.f,s2=0.f,s3=0.f,s4=0.f,s5=0.f,s6=0.f,s7=0.f;
      float q0=0.f,q1=0.f,q2=0.f,q3=0.f,q4=0.f,q5=0.f,q6=0.f,q7=0.f;
      #pragma unroll 4
      for (int k = 0; k < 64; ++k) {
        const float h1v = h1p[k * B + lane];
        const float h2v = h2p[k * B + lane];
        s0 = fmaf(w2p[0][k], h1v, s0); q0 = fmaf(u2p[0][k], h2v, q0);
        s1 = fmaf(w2p[1][k], h1v, s1); q1 = fmaf(u2p[1][k], h2v, q1);
        s2 = fmaf(w2p[2][k], h1v, s2); q2 = fmaf(u2p[2][k], h2v, q2);
        s3 = fmaf(w2p[3][k], h1v, s3); q3 = fmaf(u2p[3][k], h2v, q3);
        s4 = fmaf(w2p[4][k], h1v, s4); q4 = fmaf(u2p[4][k], h2v, q4);
        s5 = fmaf(w2p[5][k], h1v, s5); q5 = fmaf(u2p[5][k], h2v, q5);
        s6 = fmaf(w2p[6][k], h1v, s6); q6 = fmaf(u2p[6][k], h2v, q6);
        s7 = fmaf(w2p[7][k], h1v, s7); q7 = fmaf(u2p[7][k], h2v, q7);
      }
      red[wvu][0][lane]=s0+q0; red[wvu][1][lane]=s1+q1;
      red[wvu][2][lane]=s2+q2; red[wvu][3][lane]=s3+q3;
      red[wvu][4][lane]=s4+q4; red[wvu][5][lane]=s5+q5;
      red[wvu][6][lane]=s6+q6; red[wvu][7][lane]=s7+q7;
    }
    __syncthreads();

    if (tid < JPW * B) {
      const int jl = tid >> 6, b = tid & 63;
      float gate[4];
      #pragma unroll
      for (int g = 0; g < 4; ++g) {
        const int r = g * 2 + jl;
        float s = bs2[r];
        #pragma unroll
        for (int w = 0; w < 8; ++w) s += red[w][r][b];
        gate[g] = s;
      }
      const float c = gate[1] * c2s[jl][b] + gate[0] * gate[2];
      c2s[jl][b] = c;
      h2new[(size_t)(j0 + jl) * B + b] = gate[3] * tanhf(c);
    }
    __syncthreads();

    if (t >= SEQT - 1) {
      ++bar;
      gbar(cnt, NWG * bar);
      if (wg == 0) {
        const float* hb2 = h2new + (size_t)(wvu * 64) * B;
        const float* lwp = lw + wvu * 64;
        float p = 0.f;
        #pragma unroll 8
        for (int j = 0; j < 64; ++j) p = fmaf(lwp[j], hb2[j * B + lane], p);
        outred[wvu][lane] = p;
        __syncthreads();
        if (tid < B) {
          float o = lbv;
          #pragma unroll
          for (int s = 0; s < 8; ++s) o += outred[s][tid];
          out[(size_t)tid * TT + t] = o;
        }
        __syncthreads();
      }
      ++bar;
      gbar(cnt, NWG * bar);
    }
  }
}

extern "C" void kernel_launch(void* const* d_in, const int* in_sizes, int n_in,
                              void* d_out, int out_size, void* d_ws, size_t ws_size,
                              hipStream_t stream) {
  (void)in_sizes; (void)n_in; (void)out_size;
  const float* x   = (const float*)d_in[0];
  const float* W1  = (const float*)d_in[1];
  const float* bW1 = (const float*)d_in[2];
  const float* U1  = (const float*)d_in[3];
  const float* bU1 = (const float*)d_in[4];
  const float* W2  = (const float*)d_in[5];
  const float* bW2 = (const float*)d_in[6];
  const float* U2  = (const float*)d_in[7];
  const float* bU2 = (const float*)d_in[8];
  const float* lw  = (const float*)d_in[9];
  const float* lb  = (const float*)d_in[10];

  float* out = (float*)d_out;
  float* ws  = (float*)d_ws;

  if (ws_size >= (size_t)WS_TOT_F * sizeof(float)) {
    prep_ws<<<(WS_TOT_F + 255) / 256, 256, 0, stream>>>(x, U1, W2, U2, ws);
    rnn_main<<<NWG, TPB1, 0, stream>>>(W1, bW1, bU1, bW2, bU2, lw, lb, out,
                                       (int*)ws, ws + WS_H1_F, ws + WS_H2_F,
                                       ws + WS_BLOB_F, ws + WS_XT_F);
  } else {
    const int nzero = 16 + 4 * HID * B;
    zero_ws<<<(nzero + TPB - 1) / TPB, TPB, 0, stream>>>(ws, nzero);
    rnn_fallback<<<NWG, TPB, 0, stream>>>(x, W1, bW1, U1, bU1,
                                          W2, bW2, U2, bU2, lw, lb, out, ws);
  }
}

// Round 8
// 11812.195 us; speedup vs baseline: 3.8448x; 1.0443x over previous
//
#include <hip/hip_runtime.h>
#include <math.h>

#define HID 512
#define B 64
#define SEQT 1024
#define FUT 16
#define TT (SEQT + FUT)
#define NWG 256
#define TPB 512          // fallback path block size
#define TPB1 1024        // main kernel block size (16 waves, 4/SIMD)
#define NWAVE1 16
#define JPW 2            // hidden units owned per WG = HID/NWG
#define HB (HID * B)     // one h buffer, floats
#define BLOBF 12288      // floats per WG: 4096 (phase1) + 8192 (phase2)

// ws float layout (main path):
//   [0..511]               barrier block (ints): slot[wg] at int wg (wg<256)
//   [512 .. +2HB)          h1 double buffer  (float4 tiles: h4[k>>2][b][k&3])
//   [.. +2HB)              h2 double buffer  (same layout)
//   [.. +NWG*BLOBF)        rearranged weight blobs (per WG)
//   [.. +SEQT*B)           xT (x transposed to [t][b])
//   [.. +SEQT*NWG*B)       deferred-output partials part[t][wg][b] (defer mode)
#define WS_H1_F   512
#define WS_H2_F   (WS_H1_F + 2 * HB)
#define WS_BLOB_F (WS_H2_F + 2 * HB)
#define WS_XT_F   (WS_BLOB_F + NWG * BLOBF)
#define WS_TOT_F  (WS_XT_F + SEQT * B)
#define WS_PART_F WS_TOT_F
#define WS_TOT2_F (WS_PART_F + (size_t)SEQT * NWG * B)

// publish device-wide WITHOUT buffer_wbl2 (r6 win: wbl2 writeback pushed h
// past the MALL -> every post-barrier read paid HBM latency).
__device__ inline void pub_store(float* p, float v) {
  __hip_atomic_store(p, v, __ATOMIC_RELAXED, __HIP_MEMORY_SCOPE_AGENT);
}

// ---- grid barrier v5: slot stores + EVERY WG polls all slots directly ------
// r8 change: no leader, no go-flag -> removes two serial LIC hops per step.
// Rules kept from r4-r7: no RMW arrivals; relaxed spin loads (acquire-per-poll
// = buffer_inv per poll = L2 dead); ONE pre-spin acquire fence (inv) per WG.
__device__ inline void gbar5(int* bb, int wg, int bar) {
  __builtin_amdgcn_s_waitcnt(0);   // all waves: drain own write-through stores
  __syncthreads();
  const int tid = threadIdx.x;
  if (tid == 0) {
    __hip_atomic_store(bb + wg, bar, __ATOMIC_RELAXED, __HIP_MEMORY_SCOPE_AGENT);
    __builtin_amdgcn_fence(__ATOMIC_ACQUIRE, "agent");  // pre-spin inv, once
  }
  if (tid < 64) {                  // wave 0: poll all 256 arrival slots
    for (;;) {
      int a = __hip_atomic_load(bb + tid,       __ATOMIC_RELAXED, __HIP_MEMORY_SCOPE_AGENT);
      int b = __hip_atomic_load(bb + 64  + tid, __ATOMIC_RELAXED, __HIP_MEMORY_SCOPE_AGENT);
      int c = __hip_atomic_load(bb + 128 + tid, __ATOMIC_RELAXED, __HIP_MEMORY_SCOPE_AGENT);
      int d = __hip_atomic_load(bb + 192 + tid, __ATOMIC_RELAXED, __HIP_MEMORY_SCOPE_AGENT);
      if (__all(a >= bar && b >= bar && c >= bar && d >= bar)) break;
      __builtin_amdgcn_s_sleep(1);
    }
  }
  __syncthreads();  // h loads below stay below
}

// ---------------- prep: zero state, rearrange weights, transpose x -----------
__global__ void __launch_bounds__(256) prep_ws(
    const float* __restrict__ x,
    const float* __restrict__ U1, const float* __restrict__ W2,
    const float* __restrict__ U2, float* __restrict__ ws)
{
  const int idx = blockIdx.x * blockDim.x + threadIdx.x;
  if (idx < WS_BLOB_F) {                       // barrier block + h buffers
    ws[idx] = 0.0f;
  }
  {
    const int i2 = idx - WS_BLOB_F;
    if (i2 >= 0 && i2 < NWG * BLOBF) {
      const int wg  = i2 / BLOBF;
      const int off = i2 - wg * BLOBF;
      const int j0  = wg * JPW;
      float v;
      if (off < 4096) {                        // phase1: [k*8 + r] = U1[row(r)][k]
        const int k = off >> 3, r = off & 7;
        const int row = (r >> 1) * HID + j0 + (r & 1);
        v = U1[(size_t)row * HID + k];
      } else {                                 // phase2: [k*16 + rr]
        const int o2 = off - 4096;
        const int k = o2 >> 4, rr = o2 & 15;
        const int r = rr & 7;
        const int row = (r >> 1) * HID + j0 + (r & 1);
        v = (rr < 8) ? W2[(size_t)row * HID + k] : U2[(size_t)row * HID + k];
      }
      ws[WS_BLOB_F + i2] = v;
    }
  }
  {
    const int i3 = idx - WS_XT_F;
    if (i3 >= 0 && i3 < SEQT * B) {
      const int t = i3 >> 6, b = i3 & 63;
      ws[WS_XT_F + i3] = x[(size_t)b * SEQT + t];
    }
  }
}

// -------- persistent 2-layer LSTM: LDS weights, register-carried h1 ----------
// 16 waves/WG (4/SIMD). Wave wvu owns k-chunk [wvu*32, wvu*32+32).
// phase1 uses H1 registers (h1(t-1), carried from last step's phase2 load) ->
// NO global loads before the barrier. phase2 loads H1<-h1(t), Q<-h2(t-1):
// the only post-barrier global reads (16 dwordx4/wave).
// defer mode (r8): teacher-region output head is NOT computed in the loop
// (it made one WG a per-step straggler). Instead each WG stores its 2-unit
// output partial at cell-2 (64 floats/step); a parallel tail reduces them.
__global__ void __launch_bounds__(TPB1, 1) rnn_main(
    const float* __restrict__ W1, const float* __restrict__ bW1,
    const float* __restrict__ bU1,
    const float* __restrict__ bW2, const float* __restrict__ bU2,
    const float* __restrict__ lw, const float* __restrict__ lb,
    float* __restrict__ out,
    int* __restrict__ bb,
    float* __restrict__ h1b, float* __restrict__ h2b,
    const float* __restrict__ wbl, const float* __restrict__ xT,
    float* __restrict__ part, int defer)
{
  __shared__ float wlds[BLOBF];         // 48 KB persistent weight blob
  __shared__ float red[NWAVE1][8][B];   // per-wave partial dots, 32 KB
  __shared__ float outred[NWAVE1][B];   // output-head reduction, 4 KB
  __shared__ float c1s[JPW][B], c2s[JPW][B];
  __shared__ float pout[JPW][B];        // per-step output partial staging
  __shared__ float w1c[8], bs1[8], bs2[8], lwc[JPW];

  const int wg   = blockIdx.x;
  const int j0   = wg * JPW;
  const int tid  = threadIdx.x;
  const int lane = tid & 63;
  const int wvu  = __builtin_amdgcn_readfirstlane(tid >> 6);

  // ---- one-time: copy this WG's weight blob into LDS ----
  {
    const float4* gsrc = (const float4*)(wbl + (size_t)wg * BLOBF);
    float4* ldst = (float4*)wlds;
    #pragma unroll
    for (int i = 0; i < BLOBF / 4 / TPB1; ++i)
      ldst[i * TPB1 + tid] = gsrc[i * TPB1 + tid];
  }
  if (tid < JPW * B) { c1s[tid >> 6][lane] = 0.f; c2s[tid >> 6][lane] = 0.f; }
  if (tid < 8) {
    const int g = tid >> 1, jl = tid & 1;
    const int row = g * HID + j0 + jl;
    w1c[tid] = W1[row];
    bs1[tid] = bW1[row] + bU1[row];
    bs2[tid] = bW2[row] + bU2[row];
  }
  if (tid < JPW) lwc[tid] = lw[j0 + tid];
  __syncthreads();

  const float* wl1 = wlds + wvu * 256;          // phase1 weights, this wave
  const float* wl2 = wlds + 4096 + wvu * 512;   // phase2 weights, this wave
  const float lbv = lb[0];

  float4 H1[8], Q[8];                           // h1 carry + h2old staging
  #pragma unroll
  for (int i = 0; i < 8; ++i) H1[i] = make_float4(0.f, 0.f, 0.f, 0.f);

  int bar = 0;
  for (int t = 0; t < TT; ++t) {
    float*       h1new = h1b + (t & 1) * HB;
    const float* h2old = h2b + ((t + 1) & 1) * HB;
    float*       h2new = h2b + (t & 1) * HB;

    // prefetch x for cell-1 (teacher region)
    float xvpref = 0.f;
    if (tid < JPW * B && t < SEQT) xvpref = xT[(size_t)t * B + lane];

    // -------- phase 1: gates1 = U1 h1(t-1), h1(t-1) in H1 registers ---------
    {
      float a[8] = {0.f,0.f,0.f,0.f,0.f,0.f,0.f,0.f};
      #pragma unroll
      for (int c = 0; c < 8; ++c) {             // 8 k-quads in this wave's 32-k
        const float hh[4] = {H1[c].x, H1[c].y, H1[c].z, H1[c].w};
        #pragma unroll
        for (int j = 0; j < 4; ++j) {
          const float4 wA = *(const float4*)(wl1 + c * 32 + j * 8);
          const float4 wB = *(const float4*)(wl1 + c * 32 + j * 8 + 4);
          const float h = hh[j];
          a[0] = fmaf(wA.x, h, a[0]); a[1] = fmaf(wA.y, h, a[1]);
          a[2] = fmaf(wA.z, h, a[2]); a[3] = fmaf(wA.w, h, a[3]);
          a[4] = fmaf(wB.x, h, a[4]); a[5] = fmaf(wB.y, h, a[5]);
          a[6] = fmaf(wB.z, h, a[6]); a[7] = fmaf(wB.w, h, a[7]);
        }
      }
      #pragma unroll
      for (int r = 0; r < 8; ++r) red[wvu][r][lane] = a[r];
    }
    __syncthreads();

    // cell-1 elementwise (2 j's x 64 b = 128 threads)
    if (tid < JPW * B) {
      const int jl = tid >> 6, b = tid & 63;
      const float xv = (t < SEQT) ? xvpref : out[(size_t)b * TT + (t - 1)];
      float gate[4];
      #pragma unroll
      for (int g = 0; g < 4; ++g) {
        const int r = g * 2 + jl;
        float s = bs1[r] + xv * w1c[r];
        #pragma unroll
        for (int w = 0; w < NWAVE1; ++w) s += red[w][r][b];
        gate[g] = s;
      }
      const float c = gate[1] * c1s[jl][b] + gate[0] * gate[2];
      c1s[jl][b] = c;
      const int j = j0 + jl;
      pub_store(&h1new[(size_t)(j >> 2) * (B * 4) + b * 4 + (j & 3)],
                gate[3] * tanhf(c));
    }

    ++bar;
    gbar5(bb, wg, bar);

    // non-defer mode only: duty WG computes output head inline (r7 behavior).
    if (!defer && wg == (t & 127) && t >= 1 && t <= SEQT - 1) {
      const float4* hb2 = (const float4*)h2old + (size_t)(wvu * 8) * B + lane;
      const float4* lw4 = (const float4*)lw + wvu * 8;
      float p = 0.f;
      #pragma unroll
      for (int i = 0; i < 8; ++i) {
        const float4 hv = hb2[i * B];
        const float4 wv = lw4[i];
        p = fmaf(wv.x, hv.x, p); p = fmaf(wv.y, hv.y, p);
        p = fmaf(wv.z, hv.z, p); p = fmaf(wv.w, hv.w, p);
      }
      outred[wvu][lane] = p;
      __syncthreads();
      if (tid < B) {
        float o = lbv;
        #pragma unroll
        for (int s = 0; s < NWAVE1; ++s) o += outred[s][tid];
        pub_store(&out[(size_t)tid * TT + (t - 1)], o);
      }
      __syncthreads();
    }

    // -------- phase 2: gates2 = W2 h1(t) + U2 h2(t-1) ------------------------
    // H1 <- h1(t) (kept for next step's phase 1), Q <- h2(t-1)
    {
      const float4* pp4 = (const float4*)h1new + (size_t)(wvu * 8) * B + lane;
      const float4* qq4 = (const float4*)h2old + (size_t)(wvu * 8) * B + lane;
      #pragma unroll
      for (int i = 0; i < 8; ++i) H1[i] = pp4[i * B];
      #pragma unroll
      for (int i = 0; i < 8; ++i) Q[i] = qq4[i * B];
      float a[8] = {0.f,0.f,0.f,0.f,0.f,0.f,0.f,0.f};
      #pragma unroll
      for (int c = 0; c < 8; ++c) {
        const float hp_[4] = {H1[c].x, H1[c].y, H1[c].z, H1[c].w};
        const float hq_[4] = {Q[c].x, Q[c].y, Q[c].z, Q[c].w};
        #pragma unroll
        for (int j = 0; j < 4; ++j) {
          const float4 w0 = *(const float4*)(wl2 + c * 64 + j * 16);
          const float4 w1 = *(const float4*)(wl2 + c * 64 + j * 16 + 4);
          const float4 w2 = *(const float4*)(wl2 + c * 64 + j * 16 + 8);
          const float4 w3 = *(const float4*)(wl2 + c * 64 + j * 16 + 12);
          const float hp1 = hp_[j], hq1 = hq_[j];
          a[0] = fmaf(w0.x, hp1, a[0]); a[1] = fmaf(w0.y, hp1, a[1]);
          a[2] = fmaf(w0.z, hp1, a[2]); a[3] = fmaf(w0.w, hp1, a[3]);
          a[4] = fmaf(w1.x, hp1, a[4]); a[5] = fmaf(w1.y, hp1, a[5]);
          a[6] = fmaf(w1.z, hp1, a[6]); a[7] = fmaf(w1.w, hp1, a[7]);
          a[0] = fmaf(w2.x, hq1, a[0]); a[1] = fmaf(w2.y, hq1, a[1]);
          a[2] = fmaf(w2.z, hq1, a[2]); a[3] = fmaf(w2.w, hq1, a[3]);
          a[4] = fmaf(w3.x, hq1, a[4]); a[5] = fmaf(w3.y, hq1, a[5]);
          a[6] = fmaf(w3.z, hq1, a[6]); a[7] = fmaf(w3.w, hq1, a[7]);
        }
      }
      #pragma unroll
      for (int r = 0; r < 8; ++r) red[wvu][r][lane] = a[r];
    }
    __syncthreads();

    // cell-2 elementwise
    if (tid < JPW * B) {
      const int jl = tid >> 6, b = tid & 63;
      float gate[4];
      #pragma unroll
      for (int g = 0; g < 4; ++g) {
        const int r = g * 2 + jl;
        float s = bs2[r];
        #pragma unroll
        for (int w = 0; w < NWAVE1; ++w) s += red[w][r][b];
        gate[g] = s;
      }
      const float c = gate[1] * c2s[jl][b] + gate[0] * gate[2];
      c2s[jl][b] = c;
      const float h2v = gate[3] * tanhf(c);
      const int j = j0 + jl;
      pub_store(&h2new[(size_t)(j >> 2) * (B * 4) + b * 4 + (j & 3)], h2v);
      if (defer && t < SEQT) pout[jl][b] = lwc[jl] * h2v;  // output partial
    }
    __syncthreads();  // protect red[] + publish pout

    // deferred-output partial store: 64 floats/WG/step, write-through
    if (defer && t < SEQT && tid < B) {
      pub_store(&part[((size_t)t * NWG + wg) * B + tid],
                pout[0][tid] + pout[1][tid]);
    }

    // Autoregressive region: out(t) must be globally visible before phase1(t+1)
    if (t >= SEQT - 1) {
      ++bar;
      gbar5(bb, wg, bar);
      if (wg == 0) {
        const float4* hb2 = (const float4*)h2new + (size_t)(wvu * 8) * B + lane;
        const float4* lw4 = (const float4*)lw + wvu * 8;
        float p = 0.f;
        #pragma unroll
        for (int i = 0; i < 8; ++i) {
          const float4 hv = hb2[i * B];
          const float4 wv = lw4[i];
          p = fmaf(wv.x, hv.x, p); p = fmaf(wv.y, hv.y, p);
          p = fmaf(wv.z, hv.z, p); p = fmaf(wv.w, hv.w, p);
        }
        outred[wvu][lane] = p;
        __syncthreads();
        if (tid < B) {
          float o = lbv;
          #pragma unroll
          for (int s = 0; s < NWAVE1; ++s) o += outred[s][tid];
          pub_store(&out[(size_t)tid * TT + t], o);
        }
        __syncthreads();
      }
      ++bar;
      gbar5(bb, wg, bar);
    }
  }

  // ---- defer mode tail: parallel reduction of output partials (t=0..1022) --
  if (defer) {
    ++bar;
    gbar5(bb, wg, bar);   // all partial stores visible + L2 inv'd
    for (int tt = wg; tt < SEQT - 1; tt += NWG) {
      const float* pp = part + ((size_t)tt * NWG + wvu * 16) * B + lane;
      float s = 0.f;
      #pragma unroll
      for (int i = 0; i < 16; ++i) s += pp[i * B];
      outred[wvu][lane] = s;
      __syncthreads();
      if (tid < B) {
        float o = lbv;
        #pragma unroll
        for (int v = 0; v < NWAVE1; ++v) o += outred[v][tid];
        out[(size_t)tid * TT + tt] = o;
      }
      __syncthreads();
    }
  }
}

// =================== fallback path (round-0 kernel, known correct) ===========
__device__ inline void gbar(int* cnt, int target) {
  __syncthreads();
  if (threadIdx.x == 0) {
    __threadfence();
    __hip_atomic_fetch_add(cnt, 1, __ATOMIC_RELEASE, __HIP_MEMORY_SCOPE_AGENT);
    while (__hip_atomic_load(cnt, __ATOMIC_ACQUIRE, __HIP_MEMORY_SCOPE_AGENT) < target) {
      __builtin_amdgcn_s_sleep(2);
    }
  }
  __syncthreads();
}

__global__ void __launch_bounds__(TPB) zero_ws(float* ws, int n) {
  int i = blockIdx.x * blockDim.x + threadIdx.x;
  if (i < n) ws[i] = 0.0f;
}

__global__ void __launch_bounds__(TPB) rnn_fallback(
    const float* __restrict__ x,
    const float* __restrict__ W1, const float* __restrict__ bW1,
    const float* __restrict__ U1, const float* __restrict__ bU1,
    const float* __restrict__ W2, const float* __restrict__ bW2,
    const float* __restrict__ U2, const float* __restrict__ bU2,
    const float* __restrict__ lw, const float* __restrict__ lb,
    float* out, float* ws)
{
  __shared__ float red[8][8][B];
  __shared__ float outred[8][B];
  __shared__ float c1s[JPW][B], c2s[JPW][B];
  __shared__ float w1c[8], bs1[8], bs2[8];

  int* cnt   = (int*)ws;
  float* h1b = ws + 16;
  float* h2b = h1b + 2 * HB;

  const int wg   = blockIdx.x;
  const int j0   = wg * JPW;
  const int tid  = threadIdx.x;
  const int lane = tid & 63;
  const int wvu  = __builtin_amdgcn_readfirstlane(tid >> 6);
  const int kb   = wvu << 6;

  if (tid < JPW * B) { c1s[tid >> 6][lane] = 0.f; c2s[tid >> 6][lane] = 0.f; }
  if (tid < 8) {
    const int g = tid >> 1, jl = tid & 1;
    const int row = g * HID + j0 + jl;
    w1c[tid] = W1[row];
    bs1[tid] = bW1[row] + bU1[row];
    bs2[tid] = bW2[row] + bU2[row];
  }
  __syncthreads();

  const float* u1p[8]; const float* w2p[8]; const float* u2p[8];
  #pragma unroll
  for (int r = 0; r < 8; ++r) {
    const int row = (r >> 1) * HID + j0 + (r & 1);
    u1p[r] = U1 + (size_t)row * HID + kb;
    w2p[r] = W2 + (size_t)row * HID + kb;
    u2p[r] = U2 + (size_t)row * HID + kb;
  }
  const float lbv = lb[0];

  int bar = 0;
  for (int t = 0; t < TT; ++t) {
    const float* h1old = h1b + ((t + 1) & 1) * HB;
    float*       h1new = h1b + (t & 1) * HB;
    const float* h2old = h2b + ((t + 1) & 1) * HB;
    float*       h2new = h2b + (t & 1) * HB;

    {
      const float* hp = h1old + (size_t)kb * B;
      float a0=0.f,a1=0.f,a2=0.f,a3=0.f,a4=0.f,a5=0.f,a6=0.f,a7=0.f;
      #pragma unroll 8
      for (int k = 0; k < 64; ++k) {
        const float hv = hp[k * B + lane];
        a0 = fmaf(u1p[0][k], hv, a0); a1 = fmaf(u1p[1][k], hv, a1);
        a2 = fmaf(u1p[2][k], hv, a2); a3 = fmaf(u1p[3][k], hv, a3);
        a4 = fmaf(u1p[4][k], hv, a4); a5 = fmaf(u1p[5][k], hv, a5);
        a6 = fmaf(u1p[6][k], hv, a6); a7 = fmaf(u1p[7][k], hv, a7);
      }
      red[wvu][0][lane]=a0; red[wvu][1][lane]=a1; red[wvu][2][lane]=a2; red[wvu][3][lane]=a3;
      red[wvu][4][lane]=a4; red[wvu][5][lane]=a5; red[wvu][6][lane]=a6; red[wvu][7][lane]=a7;
    }
    __syncthreads();

    if (tid < JPW * B) {
      const int jl = tid >> 6, b = tid & 63;
      const float xv = (t < SEQT) ? x[(size_t)b * SEQT + t]
                                  : out[(size_t)b * TT + (t - 1)];
      float gate[4];
      #pragma unroll
      for (int g = 0; g < 4; ++g) {
        const int r = g * 2 + jl;
        float s = bs1[r] + xv * w1c[r];
        #pragma unroll
        for (int w = 0; w < 8; ++w) s += red[w][r][b];
        gate[g] = s;
      }
      const float c = gate[1] * c1s[jl][b] + gate[0] * gate[2];
      c1s[jl][b] = c;
      h1new[(size_t)(j0 + jl) * B + b] = gate[3] * tanhf(c);
    }

    ++bar;
    gbar(cnt, NWG * bar);

    if (wg == 0 && t >= 1 && t <= SEQT - 1) {
      const float* hb2 = h2old + (size_t)(wvu * 64) * B;
      const float* lwp = lw + wvu * 64;
      float p = 0.f;
      #pragma unroll 8
      for (int j = 0; j < 64; ++j) p = fmaf(lwp[j], hb2[j * B + lane], p);
      outred[wvu][lane] = p;
      __syncthreads();
      if (tid < B) {
        float o = lbv;
        #pragma unroll
        for (int s = 0; s < 8; ++s) o += outred[s][tid];
        out[(size_t)tid * TT + (t - 1)] = o;
      }
      __syncthreads();
    }

    {
      const float* h1p = h1new + (size_t)kb * B;
      const float* h2p = h2old + (size_t)kb * B;
      float s0=0.f,s1=0.f,s2=0.f,s3=0.f,s4=0.f,s5=0.f,s6=0.f,s7=0.f;
      float q0=0.f,q1=0.f,q2=0.f,q3=0.f,q4=0.f,q5=0.f,q6=0.f,q7=0.f;
      #pragma unroll 4
      for (int k = 0; k < 64; ++k) {
        const float h1v = h1p[k * B + lane];
        const float h2v = h2p[k * B + lane];
        s0 = fmaf(w2p[0][k], h1v, s0); q0 = fmaf(u2p[0][k], h2v, q0);
        s1 = fmaf(w2p[1][k], h1v, s1); q1 = fmaf(u2p[1][k], h2v, q1);
        s2 = fmaf(w2p[2][k], h1v, s2); q2 = fmaf(u2p[2][k], h2v, q2);
        s3 = fmaf(w2p[3][k], h1v, s3); q3 = fmaf(u2p[3][k], h2v, q3);
        s4 = fmaf(w2p[4][k], h1v, s4); q4 = fmaf(u2p[4][k], h2v, q4);
        s5 = fmaf(w2p[5][k], h1v, s5); q5 = fmaf(u2p[5][k], h2v, q5);
        s6 = fmaf(w2p[6][k], h1v, s6); q6 = fmaf(u2p[6][k], h2v, q6);
        s7 = fmaf(w2p[7][k], h1v, s7); q7 = fmaf(u2p[7][k], h2v, q7);
      }
      red[wvu][0][lane]=s0+q0; red[wvu][1][lane]=s1+q1;
      red[wvu][2][lane]=s2+q2; red[wvu][3][lane]=s3+q3;
      red[wvu][4][lane]=s4+q4; red[wvu][5][lane]=s5+q5;
      red[wvu][6][lane]=s6+q6; red[wvu][7][lane]=s7+q7;
    }
    __syncthreads();

    if (tid < JPW * B) {
      const int jl = tid >> 6, b = tid & 63;
      float gate[4];
      #pragma unroll
      for (int g = 0; g < 4; ++g) {
        const int r = g * 2 + jl;
        float s = bs2[r];
        #pragma unroll
        for (int w = 0; w < 8; ++w) s += red[w][r][b];
        gate[g] = s;
      }
      const float c = gate[1] * c2s[jl][b] + gate[0] * gate[2];
      c2s[jl][b] = c;
      h2new[(size_t)(j0 + jl) * B + b] = gate[3] * tanhf(c);
    }
    __syncthreads();

    if (t >= SEQT - 1) {
      ++bar;
      gbar(cnt, NWG * bar);
      if (wg == 0) {
        const float* hb2 = h2new + (size_t)(wvu * 64) * B;
        const float* lwp = lw + wvu * 64;
        float p = 0.f;
        #pragma unroll 8
        for (int j = 0; j < 64; ++j) p = fmaf(lwp[j], hb2[j * B + lane], p);
        outred[wvu][lane] = p;
        __syncthreads();
        if (tid < B) {
          float o = lbv;
          #pragma unroll
          for (int s = 0; s < 8; ++s) o += outred[s][tid];
          out[(size_t)tid * TT + t] = o;
        }
        __syncthreads();
      }
      ++bar;
      gbar(cnt, NWG * bar);
    }
  }
}

extern "C" void kernel_launch(void* const* d_in, const int* in_sizes, int n_in,
                              void* d_out, int out_size, void* d_ws, size_t ws_size,
                              hipStream_t stream) {
  (void)in_sizes; (void)n_in; (void)out_size;
  const float* x   = (const float*)d_in[0];
  const float* W1  = (const float*)d_in[1];
  const float* bW1 = (const float*)d_in[2];
  const float* U1  = (const float*)d_in[3];
  const float* bU1 = (const float*)d_in[4];
  const float* W2  = (const float*)d_in[5];
  const float* bW2 = (const float*)d_in[6];
  const float* U2  = (const float*)d_in[7];
  const float* bU2 = (const float*)d_in[8];
  const float* lw  = (const float*)d_in[9];
  const float* lb  = (const float*)d_in[10];

  float* out = (float*)d_out;
  float* ws  = (float*)d_ws;

  if (ws_size >= (size_t)WS_TOT_F * sizeof(float)) {
    const int defer = (ws_size >= WS_TOT2_F * sizeof(float)) ? 1 : 0;
    prep_ws<<<(WS_TOT_F + 255) / 256, 256, 0, stream>>>(x, U1, W2, U2, ws);
    rnn_main<<<NWG, TPB1, 0, stream>>>(W1, bW1, bU1, bW2, bU2, lw, lb, out,
                                       (int*)ws, ws + WS_H1_F, ws + WS_H2_F,
                                       ws + WS_BLOB_F, ws + WS_XT_F,
                                       ws + WS_PART_F, defer);
  } else {
    const int nzero = 16 + 4 * HID * B;
    zero_ws<<<(nzero + TPB - 1) / TPB, TPB, 0, stream>>>(ws, nzero);
    rnn_fallback<<<NWG, TPB, 0, stream>>>(x, W1, bW1, U1, bU1,
                                          W2, bW2, U2, bU2, lw, lb, out, ws);
  }
}